// Round 8
// baseline (350.207 us; speedup 1.0000x reference)
//
#include <hip/hip_runtime.h>
#include <hip/hip_bf16.h>
#include <math.h>

#define NTOK  32768
#define GNEPS 1e-5f

typedef __attribute__((ext_vector_type(4))) float f32x4;
typedef __attribute__((ext_vector_type(8))) short s16x8;
typedef __attribute__((ext_vector_type(4))) unsigned short u16x4;

__device__ __forceinline__ unsigned short f2b(float f) {
  unsigned int u = __float_as_uint(f);
  unsigned int r = (u + 0x7FFFu + ((u >> 16) & 1u)) >> 16;
  return (unsigned short)r;
}
__device__ __forceinline__ float b2f(unsigned short s) {
  return __uint_as_float(((unsigned int)s) << 16);
}
// order-preserving float<->uint for atomicMax
__device__ __forceinline__ unsigned int fenc(float f) {
  unsigned int u = __float_as_uint(f);
  return (u & 0x80000000u) ? ~u : (u | 0x80000000u);
}
__device__ __forceinline__ float fdec(unsigned int k) {
  unsigned int u = (k & 0x80000000u) ? (k ^ 0x80000000u) : ~k;
  return __uint_as_float(u);
}

__device__ __forceinline__ void stage16(const unsigned short* g, unsigned short* ldsChunkBase, int lane) {
#if __has_builtin(__builtin_amdgcn_global_load_lds)
  __builtin_amdgcn_global_load_lds((const __attribute__((address_space(1))) void*)g,
                                   (__attribute__((address_space(3))) void*)ldsChunkBase, 16, 0, 0);
#else
  *(s16x8*)((char*)ldsChunkBase + lane * 16) = *(const s16x8*)g;
#endif
}

// ---- workspace layout (bytes) ----
#define OFF_GSTAT   0u                // 32 f32
#define OFF_KMK     128u              // 1024 u32 encoded k row max
#define OFF_SSUM    4224u             // 1024 f32 k-softmax denominators
#define OFF_CTX     8320u             // 4*8*32*32 f32 = 131072 (unnormalized)
#define OFF_WCTXB   139392u           // 4*256*256 bf16 = 524288
#define OFF_BIASP   663680u           // 4*768 f32 = 12288
#define OFF_WP      675968u           // 4*768*256 bf16 = 1572864
#define OFF_XT      2248832u          // 4*32768*256 bf16 = 67108864 (raw x, [n][c])
#define OFF_QT      69357696u         // 4*32768*256 bf16 = 67108864 (SOFTMAXED q, [n][c'])
#define OFF_KVB     136466560u        // 4*512*32768 bf16 = 134217728
#define WS_NEEDED   (OFF_KVB + 134217728ull)

// ------------------------------------------------------------------
// K1: fused GN stats + raw-x bf16 cast + transpose -> xT [b][n][c]
// ------------------------------------------------------------------
__global__ __launch_bounds__(256) void gn_fused(const float* __restrict__ x,
                                                float* __restrict__ gstat,
                                                unsigned short* __restrict__ xT) {
  __shared__ unsigned short s1[256 * 68];
  __shared__ float rs[4][4], rq[4][4];
  int b = blockIdx.y;
  int n0 = blockIdx.x * 64;
  int tid = threadIdx.x;
  const float* xb = x + (size_t)b * 256 * NTOK;
  float s[4] = {0.f, 0.f, 0.f, 0.f}, sq[4] = {0.f, 0.f, 0.f, 0.f};
#pragma unroll
  for (int it = 0; it < 16; ++it) {
    int idx = tid + it * 256;          // 4096 = 256c x 16 quads
    int c = idx >> 4, q = idx & 15;
    f32x4 v = *reinterpret_cast<const f32x4*>(&xb[(size_t)c * NTOK + n0 + q * 4]);
    const int g = it >> 2;             // compile-time group
    s[g]  += v.x + v.y + v.z + v.w;
    sq[g] += v.x * v.x + v.y * v.y + v.z * v.z + v.w * v.w;
    u16x4 o = { f2b(v.x), f2b(v.y), f2b(v.z), f2b(v.w) };
    *reinterpret_cast<u16x4*>(&s1[c * 68 + q * 4]) = o;
  }
  int lane = tid & 63, w = tid >> 6;
#pragma unroll
  for (int g = 0; g < 4; ++g) {
    float a = s[g], bq = sq[g];
    for (int o = 32; o > 0; o >>= 1) { a += __shfl_down(a, o); bq += __shfl_down(bq, o); }
    if (lane == 0) { rs[w][g] = a; rq[w][g] = bq; }
  }
  __syncthreads();
  if (tid < 8) {
    int g = tid >> 1, part = tid & 1;
    float v = part ? (rq[0][g] + rq[1][g] + rq[2][g] + rq[3][g])
                   : (rs[0][g] + rs[1][g] + rs[2][g] + rs[3][g]);
    atomicAdd(&gstat[2 * (b * 4 + g) + part], v);
  }
#pragma unroll
  for (int it = 0; it < 8; ++it) {
    int task = tid + it * 256;         // 2048 = 64n x 32 octets
    int n = task >> 5, oc = task & 31;
    s16x8 pk;
#pragma unroll
    for (int i = 0; i < 8; ++i) pk[i] = (short)s1[(oc * 8 + i) * 68 + n];
    *reinterpret_cast<s16x8*>(&xT[((size_t)(b * NTOK + n0 + n)) * 256 + oc * 8]) = pk;
  }
}

// ------------------------------------------------------------------
// K2: finalize stats + fold GN into weights
// ------------------------------------------------------------------
__global__ __launch_bounds__(256) void fold_w(const float* __restrict__ wqkv,
                                              const float* __restrict__ gamma,
                                              const float* __restrict__ beta,
                                              const float* __restrict__ gstat,
                                              unsigned short* __restrict__ Wp,
                                              float* __restrict__ biasp) {
  int o = blockIdx.x, b = blockIdx.y;
  int c = threadIdx.x;
  int g = c >> 6;
  const float cnt = 64.f * (float)NTOK;
  float mu  = gstat[2 * (b * 4 + g)] / cnt;
  float var = gstat[2 * (b * 4 + g) + 1] / cnt - mu * mu;
  float rsig = rsqrtf(var + GNEPS);
  float wv = wqkv[(size_t)o * 256 + c];
  float A = gamma[c] * rsig;
  float Bc = beta[c] - mu * A;
  Wp[((size_t)b * 768 + o) * 256 + c] = f2b(wv * A);
  float t = wv * Bc;
  int lane = c & 63, w = c >> 6;
  for (int off = 32; off > 0; off >>= 1) t += __shfl_down(t, off);
  __shared__ float red[4];
  if (lane == 0) red[w] = t;
  __syncthreads();
  if (c == 0) biasp[b * 768 + o] = red[0] + red[1] + red[2] + red[3];
}

// ------------------------------------------------------------------
// K3: qkv GEMM, 256x128 tile, 512 thr, BK=64, DOUBLE-BUFFERED (96KB LDS):
// stage(t+1) issued BEFORE compute(t); single barrier per K-step ->
// HBM transfer overlaps MFMA. Epilogues as r7 (q softmax -> qT, k/v -> kvb,
// fused k row-max).
// ------------------------------------------------------------------
__global__ __launch_bounds__(512) void qkv_gemm(const unsigned short* __restrict__ Wp,
                                                const float* __restrict__ biasp,
                                                const unsigned short* __restrict__ xT,
                                                unsigned short* __restrict__ qT,
                                                unsigned short* __restrict__ kvb,
                                                unsigned int* __restrict__ kmk) {
  __shared__ unsigned short smem[49152];   // 96KB: buf{0,1} x (A 16384 u16 + B 8192 u16)
  int bid = blockIdx.x;
  int L = (bid & 7) * 384 + (bid >> 3);    // chunked XCD swizzle (3072 = 8*384)
  int ot = L % 3;                          // q/k/v — adjacent L share (b,nt) => same XCD L2
  int t2 = L / 3;
  int b = t2 & 3, nt = t2 >> 2;
  int n0 = nt * 128;
  int tid = threadIdx.x;
  int w = tid >> 6, l = tid & 63;
  int hi = (l >> 4) & 3, lo = l & 15;
  int wo = w >> 1, wn = w & 1;
  int lr = l >> 3, lj = l & 7;
  int srcj = lj ^ lr;                      // pre-swizzled source slot
  const unsigned short* Abase = Wp + ((size_t)(b * 768 + ot * 256)) * 256;
  const unsigned short* Bbase = xT + ((size_t)(b * NTOK + n0)) * 256;

  f32x4 acc[4][4];
#pragma unroll
  for (int s = 0; s < 4; ++s)
#pragma unroll
    for (int n = 0; n < 4; ++n) acc[s][n] = (f32x4){0.f, 0.f, 0.f, 0.f};

  auto stage = [&](int buf, int c0) {
    unsigned short* As = smem + buf * 24576;
    unsigned short* Bs = As + 16384;
#pragma unroll
    for (int q = 0; q < 4; ++q) {          // A: 32 chunks of 1KB
      int chunk = w * 4 + q; int row = chunk * 8 + lr;
      stage16(Abase + (size_t)row * 256 + c0 + srcj * 8, As + chunk * 512, l);
    }
#pragma unroll
    for (int q = 0; q < 2; ++q) {          // B: 16 chunks
      int chunk = w * 2 + q; int row = chunk * 8 + lr;
      stage16(Bbase + (size_t)row * 256 + c0 + srcj * 8, Bs + chunk * 512, l);
    }
  };

  stage(0, 0);
  __syncthreads();                          // buf0 ready
  for (int step = 0; step < 4; ++step) {
    int cur = step & 1;
    if (step < 3) stage(cur ^ 1, (step + 1) * 64);   // prefetch overlaps compute
    const unsigned short* As = smem + cur * 24576;
    const unsigned short* Bs = As + 16384;
#pragma unroll
    for (int t = 0; t < 2; ++t) {
      s16x8 af[4], bf[4];
#pragma unroll
      for (int s = 0; s < 4; ++s) {
        int row = wo * 64 + s * 16 + lo;
        int phys = (t * 4 + hi) ^ (row & 7);
        af[s] = *reinterpret_cast<const s16x8*>(&As[row * 64 + phys * 8]);
      }
#pragma unroll
      for (int n = 0; n < 4; ++n) {
        int row = wn * 64 + n * 16 + lo;
        int phys = (t * 4 + hi) ^ (row & 7);
        bf[n] = *reinterpret_cast<const s16x8*>(&Bs[row * 64 + phys * 8]);
      }
#pragma unroll
      for (int s = 0; s < 4; ++s)
#pragma unroll
        for (int n = 0; n < 4; ++n)
          acc[s][n] = __builtin_amdgcn_mfma_f32_16x16x32_bf16(af[s], bf[n], acc[s][n], 0, 0, 0);
    }
    __syncthreads();                        // drains prefetch; buf[cur^1] ready, buf[cur] free
  }

  // bias add
#pragma unroll
  for (int s = 0; s < 4; ++s)
#pragma unroll
    for (int i = 0; i < 4; ++i) {
      float bv = biasp[b * 768 + ot * 256 + wo * 64 + s * 16 + hi * 4 + i];
#pragma unroll
      for (int n = 0; n < 4; ++n) acc[s][n][i] += bv;
    }

  // fused k row-max (ot==1)
  if (ot == 1) {
#pragma unroll
    for (int s = 0; s < 4; ++s)
#pragma unroll
      for (int i = 0; i < 4; ++i) {
        float m = fmaxf(fmaxf(acc[s][0][i], acc[s][1][i]), fmaxf(acc[s][2][i], acc[s][3][i]));
        m = fmaxf(m, __shfl_xor(m, 1));
        m = fmaxf(m, __shfl_xor(m, 2));
        m = fmaxf(m, __shfl_xor(m, 4));
        m = fmaxf(m, __shfl_xor(m, 8));
        if (lo == 0)
          atomicMax(&kmk[b * 256 + wo * 64 + s * 16 + hi * 4 + i], fenc(m));
      }
  }

  // ---- epilogue (bounce aliases smem) ----
  if (ot == 0) {
    // q: transpose -> bounce [64n][264], softmax over d per head, store qT[n][o]
    for (int r = 0; r < 2; ++r) {
      __syncthreads();
      if (wn == r) {
#pragma unroll
        for (int s = 0; s < 4; ++s)
#pragma unroll
          for (int n = 0; n < 4; ++n)
#pragma unroll
            for (int i = 0; i < 4; ++i) {
              int o_l = wo * 64 + s * 16 + hi * 4 + i;   // 0..255
              int n_l = n * 16 + lo;                     // 0..63
              smem[n_l * 264 + o_l] = f2b(acc[s][n][i]);
            }
      }
      __syncthreads();
      // softmax over d within head: 512 tasks = 64n x 8h
      {
        int n_l = tid >> 3, h = tid & 7;
        unsigned short* rowp = &smem[n_l * 264 + h * 32];
        float v[32];
        float m = -1e30f;
#pragma unroll
        for (int i = 0; i < 32; ++i) { v[i] = b2f(rowp[i]); m = fmaxf(m, v[i]); }
        float ssum = 0.f;
#pragma unroll
        for (int i = 0; i < 32; ++i) { v[i] = __expf(v[i] - m); ssum += v[i]; }
        float rr = 1.f / ssum;
#pragma unroll
        for (int i = 0; i < 32; ++i) rowp[i] = f2b(v[i] * rr);
      }
      __syncthreads();
#pragma unroll
      for (int it = 0; it < 4; ++it) {
        int task = tid + it * 512;                        // 2048 = 64n x 32 slots
        int n_l = task >> 5, j = task & 31;
        s16x8 v = *reinterpret_cast<const s16x8*>(&smem[n_l * 264 + j * 8]);
        *reinterpret_cast<s16x8*>(&qT[((size_t)(b * NTOK + n0 + r * 64 + n_l)) * 256 + j * 8]) = v;
      }
    }
  } else {
    // k/v: [row][n], 2 rounds over wo pairs; bounce [128o][136]
    int vbase = (ot == 1) ? 0 : 256;
    for (int r = 0; r < 2; ++r) {
      __syncthreads();
      if ((wo >> 1) == r) {
#pragma unroll
        for (int s = 0; s < 4; ++s)
#pragma unroll
          for (int n = 0; n < 4; ++n)
#pragma unroll
            for (int i = 0; i < 4; ++i) {
              int o_l = (wo & 1) * 64 + s * 16 + hi * 4 + i;  // 0..127
              int n_l = wn * 64 + n * 16 + lo;                // 0..127
              smem[o_l * 136 + n_l] = f2b(acc[s][n][i]);
            }
      }
      __syncthreads();
#pragma unroll
      for (int it = 0; it < 4; ++it) {
        int task = tid + it * 512;                        // 2048 = 128o x 16 slots
        int o_l = task >> 4, j = task & 15;
        s16x8 v = *reinterpret_cast<const s16x8*>(&smem[o_l * 136 + j * 8]);
        int row = vbase + r * 128 + o_l;
        *reinterpret_cast<s16x8*>(&kvb[((size_t)(b * 512 + row)) * NTOK + n0 + j * 8]) = v;
      }
    }
  }
}

// ------------------------------------------------------------------
// K4: ctx~ += sum_n exp(k-kmax)[d][n] * v[e][n];  Ssum += sum_n exp
// f32x4 LDS reads in the compute loop (4x fewer LDS instructions).
// ------------------------------------------------------------------
__global__ __launch_bounds__(256) void context_partial(const unsigned short* __restrict__ kvb,
                                                       const unsigned int* __restrict__ kmk,
                                                       float* __restrict__ ctx,
                                                       float* __restrict__ Ssum) {
  int bh = blockIdx.y;
  int b = bh >> 3, h = bh & 7;
  int n0 = blockIdx.x * 1024;
  const unsigned short* kb = kvb + ((size_t)(b * 512) + h * 32) * NTOK;
  const unsigned short* vb = kvb + ((size_t)(b * 512) + 256 + h * 32) * NTOK;
  __shared__ float kt[32][260];
  __shared__ float vt[32][260];
  int tid = threadIdx.x;
  int d2 = (tid >> 4) * 2;
  int e2 = (tid & 15) * 2;
  int rbase = b * 256 + h * 32;
  float acc[2][2] = {};
  float psum[4] = {0.f, 0.f, 0.f, 0.f};
  for (int sub = 0; sub < 4; ++sub) {
    int nb = n0 + sub * 256;
    __syncthreads();
#pragma unroll
    for (int it = 0; it < 4; ++it) {
      int u = tid + it * 256;
      int d = u >> 5, oc = u & 31;
      float km = fdec(kmk[rbase + d]);
      s16x8 kv = *reinterpret_cast<const s16x8*>(&kb[(size_t)d * NTOK + nb + oc * 8]);
      s16x8 vv = *reinterpret_cast<const s16x8*>(&vb[(size_t)d * NTOK + nb + oc * 8]);
      float ls = 0.f;
#pragma unroll
      for (int j = 0; j < 8; ++j) {
        float pv = __expf(b2f((unsigned short)kv[j]) - km);
        kt[d][oc * 8 + j] = pv;
        ls += pv;
        vt[d][oc * 8 + j] = b2f((unsigned short)vv[j]);
      }
      psum[it] += ls;
    }
    __syncthreads();
#pragma unroll 2
    for (int t4 = 0; t4 < 64; ++t4) {
      f32x4 ka = *reinterpret_cast<const f32x4*>(&kt[d2][t4 * 4]);
      f32x4 kc = *reinterpret_cast<const f32x4*>(&kt[d2 + 1][t4 * 4]);
      f32x4 va = *reinterpret_cast<const f32x4*>(&vt[e2][t4 * 4]);
      f32x4 vc = *reinterpret_cast<const f32x4*>(&vt[e2 + 1][t4 * 4]);
#pragma unroll
      for (int j = 0; j < 4; ++j) {
        acc[0][0] += ka[j] * va[j]; acc[0][1] += ka[j] * vc[j];
        acc[1][0] += kc[j] * va[j]; acc[1][1] += kc[j] * vc[j];
      }
    }
  }
#pragma unroll
  for (int it = 0; it < 4; ++it) {
    float v = psum[it];
    v += __shfl_xor(v, 1); v += __shfl_xor(v, 2); v += __shfl_xor(v, 4);
    v += __shfl_xor(v, 8); v += __shfl_xor(v, 16);
    if ((tid & 31) == 0) {
      int d = (tid >> 5) + it * 8;
      atomicAdd(&Ssum[rbase + d], v);
    }
  }
  float* cb = ctx + (size_t)bh * 1024;
  atomicAdd(&cb[(d2)     * 32 + e2],     acc[0][0]);
  atomicAdd(&cb[(d2)     * 32 + e2 + 1], acc[0][1]);
  atomicAdd(&cb[(d2 + 1) * 32 + e2],     acc[1][0]);
  atomicAdd(&cb[(d2 + 1) * 32 + e2 + 1], acc[1][1]);
}

// ------------------------------------------------------------------
// K5: wctx_b = bf16( (1/Ssum) * wout @ ctx~ )
// ------------------------------------------------------------------
__global__ __launch_bounds__(256) void make_wctx(const float* __restrict__ wout,
                                                 const float* __restrict__ ctx,
                                                 const float* __restrict__ Ssum,
                                                 unsigned short* __restrict__ wctxb) {
  int o = blockIdx.x, b = blockIdx.y;
  int tid = threadIdx.x;
  int h = tid >> 5, d = tid & 31;
  const float* cb = ctx + ((size_t)(b * 8 + h)) * 1024 + d * 32;
  const float* wr = wout + (size_t)o * 256 + h * 32;
  float s = 0.f;
#pragma unroll
  for (int e = 0; e < 32; ++e) s += wr[e] * cb[e];
  s *= (1.f / Ssum[b * 256 + tid]);
  wctxb[((size_t)b * 256 + o) * 256 + tid] = f2b(s);
}

// ------------------------------------------------------------------
// K6: out = wctxb @ qsm + bias + x.  Pure GEMM (qT pre-softmaxed),
// 256x128 tile, 512 thr, DOUBLE-BUFFERED like K3.
// ------------------------------------------------------------------
__global__ __launch_bounds__(512) void out_gemm(const unsigned short* __restrict__ wctxb,
                                                const unsigned short* __restrict__ qT,
                                                const float* __restrict__ bout,
                                                const float* __restrict__ x,
                                                float* __restrict__ out) {
  __shared__ unsigned short smem[49152];   // 96KB double buffer
  int bid = blockIdx.x;
  int L = (bid & 7) * 128 + (bid >> 3);    // 1024 = 8*128, bijective
  int b = L >> 8, nt = L & 255;
  int n0 = nt * 128;
  int tid = threadIdx.x;
  int w = tid >> 6, l = tid & 63;
  int hi = (l >> 4) & 3, lo = l & 15;
  int wo = w >> 1, wn = w & 1;
  int lr = l >> 3, lj = l & 7;
  int srcj = lj ^ lr;
  const unsigned short* Abase = wctxb + (size_t)b * 65536;
  const unsigned short* Bbase = qT + ((size_t)(b * NTOK + n0)) * 256;

  f32x4 acc[4][4];
#pragma unroll
  for (int s = 0; s < 4; ++s)
#pragma unroll
    for (int n = 0; n < 4; ++n) acc[s][n] = (f32x4){0.f, 0.f, 0.f, 0.f};

  auto stage = [&](int buf, int c0) {
    unsigned short* As = smem + buf * 24576;
    unsigned short* Bs = As + 16384;
#pragma unroll
    for (int q = 0; q < 4; ++q) {
      int chunk = w * 4 + q; int row = chunk * 8 + lr;
      stage16(Abase + (size_t)row * 256 + c0 + srcj * 8, As + chunk * 512, l);
    }
#pragma unroll
    for (int q = 0; q < 2; ++q) {
      int chunk = w * 2 + q; int row = chunk * 8 + lr;
      stage16(Bbase + (size_t)row * 256 + c0 + srcj * 8, Bs + chunk * 512, l);
    }
  };

  stage(0, 0);
  __syncthreads();
  for (int step = 0; step < 4; ++step) {
    int cur = step & 1;
    if (step < 3) stage(cur ^ 1, (step + 1) * 64);
    const unsigned short* As = smem + cur * 24576;
    const unsigned short* Bs = As + 16384;
#pragma unroll
    for (int t = 0; t < 2; ++t) {
      s16x8 af[4], bf[4];
#pragma unroll
      for (int s = 0; s < 4; ++s) {
        int row = wo * 64 + s * 16 + lo;
        int phys = (t * 4 + hi) ^ (row & 7);
        af[s] = *reinterpret_cast<const s16x8*>(&As[row * 64 + phys * 8]);
      }
#pragma unroll
      for (int n = 0; n < 4; ++n) {
        int row = wn * 64 + n * 16 + lo;
        int phys = (t * 4 + hi) ^ (row & 7);
        bf[n] = *reinterpret_cast<const s16x8*>(&Bs[row * 64 + phys * 8]);
      }
#pragma unroll
      for (int s = 0; s < 4; ++s)
#pragma unroll
        for (int n = 0; n < 4; ++n)
          acc[s][n] = __builtin_amdgcn_mfma_f32_16x16x32_bf16(af[s], bf[n], acc[s][n], 0, 0, 0);
    }
    __syncthreads();
  }

  const float* xb = x + (size_t)b * 256 * NTOK;
#pragma unroll
  for (int s = 0; s < 4; ++s)
#pragma unroll
    for (int i = 0; i < 4; ++i) {
      int o = wo * 64 + s * 16 + hi * 4 + i;
      float bo = bout[o];
#pragma unroll
      for (int n = 0; n < 4; ++n) {
        int nn = n0 + wn * 64 + n * 16 + lo;
        out[((size_t)b * 256 + o) * NTOK + nn] = acc[s][n][i] + bo + xb[(size_t)o * NTOK + nn];
      }
    }
}

// ------------------------------------------------------------------
extern "C" void kernel_launch(void* const* d_in, const int* in_sizes, int n_in,
                              void* d_out, int out_size, void* d_ws, size_t ws_size,
                              hipStream_t stream) {
  const float* x     = (const float*)d_in[0];
  const float* gamma = (const float*)d_in[1];
  const float* beta  = (const float*)d_in[2];
  const float* wqkv  = (const float*)d_in[3];
  const float* wout  = (const float*)d_in[4];
  const float* bout  = (const float*)d_in[5];
  float* out = (float*)d_out;

  if (ws_size < WS_NEEDED) return;

  char* ws = (char*)d_ws;
  float* gstat        = (float*)(ws + OFF_GSTAT);
  unsigned int* kmk   = (unsigned int*)(ws + OFF_KMK);
  float* Ssum         = (float*)(ws + OFF_SSUM);
  float* ctx          = (float*)(ws + OFF_CTX);
  unsigned short* wctxb = (unsigned short*)(ws + OFF_WCTXB);
  float* biasp        = (float*)(ws + OFF_BIASP);
  unsigned short* Wp  = (unsigned short*)(ws + OFF_WP);
  unsigned short* xT  = (unsigned short*)(ws + OFF_XT);
  unsigned short* qT  = (unsigned short*)(ws + OFF_QT);
  unsigned short* kvb = (unsigned short*)(ws + OFF_KVB);

  // zero: gstat, kmk (0 < all encoded floats), Ssum, ctx
  hipMemsetAsync(ws, 0, OFF_CTX + 131072u, stream);

  gn_fused  <<<dim3(512, 4), 256, 0, stream>>>(x, gstat, xT);
  fold_w    <<<dim3(768, 4), 256, 0, stream>>>(wqkv, gamma, beta, gstat, Wp, biasp);
  qkv_gemm  <<<3072, 512, 0, stream>>>(Wp, biasp, xT, qT, kvb, kmk);
  context_partial<<<dim3(32, 32), 256, 0, stream>>>(kvb, kmk, ctx, Ssum);
  make_wctx <<<dim3(256, 4), 256, 0, stream>>>(wout, ctx, Ssum, wctxb);
  out_gemm  <<<1024, 512, 0, stream>>>(wctxb, qT, bout, x, out);
}

// Round 9
// 338.382 us; speedup vs baseline: 1.0349x; 1.0349x over previous
//
#include <hip/hip_runtime.h>
#include <hip/hip_bf16.h>
#include <math.h>

#define NTOK  32768
#define GNEPS 1e-5f

typedef __attribute__((ext_vector_type(4))) float f32x4;
typedef __attribute__((ext_vector_type(8))) short s16x8;
typedef __attribute__((ext_vector_type(4))) unsigned short u16x4;

__device__ __forceinline__ unsigned short f2b(float f) {
  unsigned int u = __float_as_uint(f);
  unsigned int r = (u + 0x7FFFu + ((u >> 16) & 1u)) >> 16;
  return (unsigned short)r;
}
__device__ __forceinline__ float b2f(unsigned short s) {
  return __uint_as_float(((unsigned int)s) << 16);
}
// order-preserving float<->uint for atomicMax
__device__ __forceinline__ unsigned int fenc(float f) {
  unsigned int u = __float_as_uint(f);
  return (u & 0x80000000u) ? ~u : (u | 0x80000000u);
}
__device__ __forceinline__ float fdec(unsigned int k) {
  unsigned int u = (k & 0x80000000u) ? (k ^ 0x80000000u) : ~k;
  return __uint_as_float(u);
}

__device__ __forceinline__ void stage16(const unsigned short* g, unsigned short* ldsChunkBase, int lane) {
#if __has_builtin(__builtin_amdgcn_global_load_lds)
  __builtin_amdgcn_global_load_lds((const __attribute__((address_space(1))) void*)g,
                                   (__attribute__((address_space(3))) void*)ldsChunkBase, 16, 0, 0);
#else
  *(s16x8*)((char*)ldsChunkBase + lane * 16) = *(const s16x8*)g;
#endif
}

// ---- workspace layout (bytes) ----
#define OFF_GSTAT   0u                // 32 f32
#define OFF_KMK     128u              // 1024 u32 encoded k row max
#define OFF_SSUM    4224u             // 1024 f32 k-softmax denominators
#define OFF_CTX     8320u             // 4*8*32*32 f32 = 131072 (unnormalized)
#define OFF_WCTXB   139392u           // 4*256*256 bf16 = 524288
#define OFF_BIASP   663680u           // 4*768 f32 = 12288
#define OFF_WP      675968u           // 4*768*256 bf16 = 1572864
#define OFF_XT      2248832u          // 4*32768*256 bf16 = 67108864 (raw x, [n][c])
#define OFF_QT      69357696u         // 4*32768*256 bf16 = 67108864 (SOFTMAXED q, [n][c'])
#define OFF_KVB     136466560u        // 4*512*32768 bf16 = 134217728
#define WS_NEEDED   (OFF_KVB + 134217728ull)

// ------------------------------------------------------------------
// K1: fused GN stats + raw-x bf16 cast + transpose -> xT [b][n][c]
// LDS tile s1 u16[256][64] with ROTATED columns: logical col n of row c
// stored at (n + 4*(c>>3)) & 63.  Transpose read across oc-lanes becomes
// 2-way (free) instead of 16-way.
// ------------------------------------------------------------------
__global__ __launch_bounds__(256) void gn_fused(const float* __restrict__ x,
                                                float* __restrict__ gstat,
                                                unsigned short* __restrict__ xT) {
  __shared__ unsigned short s1[256 * 64];
  __shared__ float rs[4][4], rq[4][4];
  int b = blockIdx.y;
  int n0 = blockIdx.x * 64;
  int tid = threadIdx.x;
  const float* xb = x + (size_t)b * 256 * NTOK;
  float s[4] = {0.f, 0.f, 0.f, 0.f}, sq[4] = {0.f, 0.f, 0.f, 0.f};
#pragma unroll
  for (int it = 0; it < 16; ++it) {
    int idx = tid + it * 256;          // 4096 = 256c x 16 quads
    int c = idx >> 4, q = idx & 15;
    f32x4 v = *reinterpret_cast<const f32x4*>(&xb[(size_t)c * NTOK + n0 + q * 4]);
    const int g = it >> 2;             // compile-time group
    s[g]  += v.x + v.y + v.z + v.w;
    sq[g] += v.x * v.x + v.y * v.y + v.z * v.z + v.w * v.w;
    u16x4 o = { f2b(v.x), f2b(v.y), f2b(v.z), f2b(v.w) };
    int phys = (q * 4 + (c >> 3) * 4) & 63;          // 4-aligned, no wrap within quad
    *reinterpret_cast<u16x4*>(&s1[c * 64 + phys]) = o;
  }
  int lane = tid & 63, w = tid >> 6;
#pragma unroll
  for (int g = 0; g < 4; ++g) {
    float a = s[g], bq = sq[g];
    for (int o = 32; o > 0; o >>= 1) { a += __shfl_down(a, o); bq += __shfl_down(bq, o); }
    if (lane == 0) { rs[w][g] = a; rq[w][g] = bq; }
  }
  __syncthreads();
  if (tid < 8) {
    int g = tid >> 1, part = tid & 1;
    float v = part ? (rq[0][g] + rq[1][g] + rq[2][g] + rq[3][g])
                   : (rs[0][g] + rs[1][g] + rs[2][g] + rs[3][g]);
    atomicAdd(&gstat[2 * (b * 4 + g) + part], v);
  }
#pragma unroll
  for (int it = 0; it < 8; ++it) {
    int task = tid + it * 256;         // 2048 = 64n x 32 octets
    int n = task >> 5, oc = task & 31;
    int phys = (n + oc * 4) & 63;      // rot = 4*(c>>3) = 4*oc for c in [oc*8, oc*8+8)
    s16x8 pk;
#pragma unroll
    for (int i = 0; i < 8; ++i) pk[i] = (short)s1[(oc * 8 + i) * 64 + phys];
    *reinterpret_cast<s16x8*>(&xT[((size_t)(b * NTOK + n0 + n)) * 256 + oc * 8]) = pk;
  }
}

// ------------------------------------------------------------------
// K2: finalize stats + fold GN into weights
// ------------------------------------------------------------------
__global__ __launch_bounds__(256) void fold_w(const float* __restrict__ wqkv,
                                              const float* __restrict__ gamma,
                                              const float* __restrict__ beta,
                                              const float* __restrict__ gstat,
                                              unsigned short* __restrict__ Wp,
                                              float* __restrict__ biasp) {
  int o = blockIdx.x, b = blockIdx.y;
  int c = threadIdx.x;
  int g = c >> 6;
  const float cnt = 64.f * (float)NTOK;
  float mu  = gstat[2 * (b * 4 + g)] / cnt;
  float var = gstat[2 * (b * 4 + g) + 1] / cnt - mu * mu;
  float rsig = rsqrtf(var + GNEPS);
  float wv = wqkv[(size_t)o * 256 + c];
  float A = gamma[c] * rsig;
  float Bc = beta[c] - mu * A;
  Wp[((size_t)b * 768 + o) * 256 + c] = f2b(wv * A);
  float t = wv * Bc;
  int lane = c & 63, w = c >> 6;
  for (int off = 32; off > 0; off >>= 1) t += __shfl_down(t, off);
  __shared__ float red[4];
  if (lane == 0) red[w] = t;
  __syncthreads();
  if (c == 0) biasp[b * 768 + o] = red[0] + red[1] + red[2] + red[3];
}

// ------------------------------------------------------------------
// K3: qkv GEMM, 256x128 tile (o x n), 512 thr = 8 waves (4 o-groups x 2 n).
// m97 2-barrier loop, single 48KB buffer (proven r5/r7 engine).
// Epilogue: bias; q -> SOFTMAX over d -> qT[n][o]; k/v -> kvb[row][n];
// fused k row-max.
// ------------------------------------------------------------------
__global__ __launch_bounds__(512, 4) void qkv_gemm(const unsigned short* __restrict__ Wp,
                                                   const float* __restrict__ biasp,
                                                   const unsigned short* __restrict__ xT,
                                                   unsigned short* __restrict__ qT,
                                                   unsigned short* __restrict__ kvb,
                                                   unsigned int* __restrict__ kmk) {
  __shared__ unsigned short smem[24576];   // 48KB: As [0,16384), Bs [16384,24576); epilogue bounce aliases
  unsigned short* As = smem;               // 256 rows x 64c
  unsigned short* Bs = smem + 16384;       // 128 rows x 64c
  int bid = blockIdx.x;
  int L = (bid & 7) * 384 + (bid >> 3);    // chunked XCD swizzle (3072 = 8*384)
  int ot = L % 3;                          // q/k/v — adjacent L share (b,nt) => same XCD L2
  int t2 = L / 3;
  int b = t2 & 3, nt = t2 >> 2;
  int n0 = nt * 128;
  int tid = threadIdx.x;
  int w = tid >> 6, l = tid & 63;
  int hi = (l >> 4) & 3, lo = l & 15;
  int wo = w >> 1, wn = w & 1;
  int lr = l >> 3, lj = l & 7;
  int srcj = lj ^ lr;                      // pre-swizzled source slot
  const unsigned short* Abase = Wp + ((size_t)(b * 768 + ot * 256)) * 256;
  const unsigned short* Bbase = xT + ((size_t)(b * NTOK + n0)) * 256;

  f32x4 acc[4][4];
#pragma unroll
  for (int s = 0; s < 4; ++s)
#pragma unroll
    for (int n = 0; n < 4; ++n) acc[s][n] = (f32x4){0.f, 0.f, 0.f, 0.f};

  for (int c0 = 0; c0 < 256; c0 += 64) {
    __syncthreads();
#pragma unroll
    for (int q = 0; q < 4; ++q) {          // A: 32 chunks of 1KB
      int chunk = w * 4 + q; int row = chunk * 8 + lr;
      stage16(Abase + (size_t)row * 256 + c0 + srcj * 8, As + chunk * 512, l);
    }
#pragma unroll
    for (int q = 0; q < 2; ++q) {          // B: 16 chunks
      int chunk = w * 2 + q; int row = chunk * 8 + lr;
      stage16(Bbase + (size_t)row * 256 + c0 + srcj * 8, Bs + chunk * 512, l);
    }
    __syncthreads();
#pragma unroll
    for (int t = 0; t < 2; ++t) {
      s16x8 af[4], bf[4];
#pragma unroll
      for (int s = 0; s < 4; ++s) {
        int row = wo * 64 + s * 16 + lo;
        int phys = (t * 4 + hi) ^ (row & 7);
        af[s] = *reinterpret_cast<const s16x8*>(&As[row * 64 + phys * 8]);
      }
#pragma unroll
      for (int n = 0; n < 4; ++n) {
        int row = wn * 64 + n * 16 + lo;
        int phys = (t * 4 + hi) ^ (row & 7);
        bf[n] = *reinterpret_cast<const s16x8*>(&Bs[row * 64 + phys * 8]);
      }
#pragma unroll
      for (int s = 0; s < 4; ++s)
#pragma unroll
        for (int n = 0; n < 4; ++n)
          acc[s][n] = __builtin_amdgcn_mfma_f32_16x16x32_bf16(af[s], bf[n], acc[s][n], 0, 0, 0);
    }
  }

  // bias add
#pragma unroll
  for (int s = 0; s < 4; ++s)
#pragma unroll
    for (int i = 0; i < 4; ++i) {
      float bv = biasp[b * 768 + ot * 256 + wo * 64 + s * 16 + hi * 4 + i];
#pragma unroll
      for (int n = 0; n < 4; ++n) acc[s][n][i] += bv;
    }

  // fused k row-max (ot==1): reduce over n-frags + 16 lo lanes, atomicMax
  if (ot == 1) {
#pragma unroll
    for (int s = 0; s < 4; ++s)
#pragma unroll
      for (int i = 0; i < 4; ++i) {
        float m = fmaxf(fmaxf(acc[s][0][i], acc[s][1][i]), fmaxf(acc[s][2][i], acc[s][3][i]));
        m = fmaxf(m, __shfl_xor(m, 1));
        m = fmaxf(m, __shfl_xor(m, 2));
        m = fmaxf(m, __shfl_xor(m, 4));
        m = fmaxf(m, __shfl_xor(m, 8));
        if (lo == 0)
          atomicMax(&kmk[b * 256 + wo * 64 + s * 16 + hi * 4 + i], fenc(m));
      }
  }

  // ---- epilogue (bounce aliases smem) ----
  if (ot == 0) {
    // q: transpose -> bounce [64n][264], softmax over d per head, store qT[n][o]
    for (int r = 0; r < 2; ++r) {
      __syncthreads();
      if (wn == r) {
#pragma unroll
        for (int s = 0; s < 4; ++s)
#pragma unroll
          for (int n = 0; n < 4; ++n)
#pragma unroll
            for (int i = 0; i < 4; ++i) {
              int o_l = wo * 64 + s * 16 + hi * 4 + i;   // 0..255
              int n_l = n * 16 + lo;                     // 0..63
              smem[n_l * 264 + o_l] = f2b(acc[s][n][i]);
            }
      }
      __syncthreads();
      // softmax over d within head: 512 tasks = 64n x 8h
      {
        int n_l = tid >> 3, h = tid & 7;
        unsigned short* rowp = &smem[n_l * 264 + h * 32];
        float v[32];
        float m = -1e30f;
#pragma unroll
        for (int i = 0; i < 32; ++i) { v[i] = b2f(rowp[i]); m = fmaxf(m, v[i]); }
        float ssum = 0.f;
#pragma unroll
        for (int i = 0; i < 32; ++i) { v[i] = __expf(v[i] - m); ssum += v[i]; }
        float rr = 1.f / ssum;
#pragma unroll
        for (int i = 0; i < 32; ++i) rowp[i] = f2b(v[i] * rr);
      }
      __syncthreads();
#pragma unroll
      for (int it = 0; it < 4; ++it) {
        int task = tid + it * 512;                        // 2048 = 64n x 32 slots
        int n_l = task >> 5, j = task & 31;
        s16x8 v = *reinterpret_cast<const s16x8*>(&smem[n_l * 264 + j * 8]);
        *reinterpret_cast<s16x8*>(&qT[((size_t)(b * NTOK + n0 + r * 64 + n_l)) * 256 + j * 8]) = v;
      }
    }
  } else {
    // k/v: [row][n], 2 rounds over wo pairs; bounce [128o][136]
    int vbase = (ot == 1) ? 0 : 256;
    for (int r = 0; r < 2; ++r) {
      __syncthreads();
      if ((wo >> 1) == r) {
#pragma unroll
        for (int s = 0; s < 4; ++s)
#pragma unroll
          for (int n = 0; n < 4; ++n)
#pragma unroll
            for (int i = 0; i < 4; ++i) {
              int o_l = (wo & 1) * 64 + s * 16 + hi * 4 + i;  // 0..127
              int n_l = wn * 64 + n * 16 + lo;                // 0..127
              smem[o_l * 136 + n_l] = f2b(acc[s][n][i]);
            }
      }
      __syncthreads();
#pragma unroll
      for (int it = 0; it < 4; ++it) {
        int task = tid + it * 512;                        // 2048 = 128o x 16 slots
        int o_l = task >> 4, j = task & 15;
        s16x8 v = *reinterpret_cast<const s16x8*>(&smem[o_l * 136 + j * 8]);
        int row = vbase + r * 128 + o_l;
        *reinterpret_cast<s16x8*>(&kvb[((size_t)(b * 512 + row)) * NTOK + n0 + j * 8]) = v;
      }
    }
  }
}

// ------------------------------------------------------------------
// K4: ctx~ += sum_n exp(k-kmax)[d][n] * v[e][n];  Ssum += sum_n exp
// f32x4 LDS reads in the compute loop.
// ------------------------------------------------------------------
__global__ __launch_bounds__(256) void context_partial(const unsigned short* __restrict__ kvb,
                                                       const unsigned int* __restrict__ kmk,
                                                       float* __restrict__ ctx,
                                                       float* __restrict__ Ssum) {
  int bh = blockIdx.y;
  int b = bh >> 3, h = bh & 7;
  int n0 = blockIdx.x * 1024;
  const unsigned short* kb = kvb + ((size_t)(b * 512) + h * 32) * NTOK;
  const unsigned short* vb = kvb + ((size_t)(b * 512) + 256 + h * 32) * NTOK;
  __shared__ float kt[32][260];
  __shared__ float vt[32][260];
  int tid = threadIdx.x;
  int d2 = (tid >> 4) * 2;
  int e2 = (tid & 15) * 2;
  int rbase = b * 256 + h * 32;
  float acc[2][2] = {};
  float psum[4] = {0.f, 0.f, 0.f, 0.f};
  for (int sub = 0; sub < 4; ++sub) {
    int nb = n0 + sub * 256;
    __syncthreads();
#pragma unroll
    for (int it = 0; it < 4; ++it) {
      int u = tid + it * 256;
      int d = u >> 5, oc = u & 31;
      float km = fdec(kmk[rbase + d]);
      s16x8 kv = *reinterpret_cast<const s16x8*>(&kb[(size_t)d * NTOK + nb + oc * 8]);
      s16x8 vv = *reinterpret_cast<const s16x8*>(&vb[(size_t)d * NTOK + nb + oc * 8]);
      float ls = 0.f;
#pragma unroll
      for (int j = 0; j < 8; ++j) {
        float pv = __expf(b2f((unsigned short)kv[j]) - km);
        kt[d][oc * 8 + j] = pv;
        ls += pv;
        vt[d][oc * 8 + j] = b2f((unsigned short)vv[j]);
      }
      psum[it] += ls;
    }
    __syncthreads();
#pragma unroll 2
    for (int t4 = 0; t4 < 64; ++t4) {
      f32x4 ka = *reinterpret_cast<const f32x4*>(&kt[d2][t4 * 4]);
      f32x4 kc = *reinterpret_cast<const f32x4*>(&kt[d2 + 1][t4 * 4]);
      f32x4 va = *reinterpret_cast<const f32x4*>(&vt[e2][t4 * 4]);
      f32x4 vc = *reinterpret_cast<const f32x4*>(&vt[e2 + 1][t4 * 4]);
#pragma unroll
      for (int j = 0; j < 4; ++j) {
        acc[0][0] += ka[j] * va[j]; acc[0][1] += ka[j] * vc[j];
        acc[1][0] += kc[j] * va[j]; acc[1][1] += kc[j] * vc[j];
      }
    }
  }
#pragma unroll
  for (int it = 0; it < 4; ++it) {
    float v = psum[it];
    v += __shfl_xor(v, 1); v += __shfl_xor(v, 2); v += __shfl_xor(v, 4);
    v += __shfl_xor(v, 8); v += __shfl_xor(v, 16);
    if ((tid & 31) == 0) {
      int d = (tid >> 5) + it * 8;
      atomicAdd(&Ssum[rbase + d], v);
    }
  }
  float* cb = ctx + (size_t)bh * 1024;
  atomicAdd(&cb[(d2)     * 32 + e2],     acc[0][0]);
  atomicAdd(&cb[(d2)     * 32 + e2 + 1], acc[0][1]);
  atomicAdd(&cb[(d2 + 1) * 32 + e2],     acc[1][0]);
  atomicAdd(&cb[(d2 + 1) * 32 + e2 + 1], acc[1][1]);
}

// ------------------------------------------------------------------
// K5: wctx_b = bf16( (1/Ssum) * wout @ ctx~ )
// ------------------------------------------------------------------
__global__ __launch_bounds__(256) void make_wctx(const float* __restrict__ wout,
                                                 const float* __restrict__ ctx,
                                                 const float* __restrict__ Ssum,
                                                 unsigned short* __restrict__ wctxb) {
  int o = blockIdx.x, b = blockIdx.y;
  int tid = threadIdx.x;
  int h = tid >> 5, d = tid & 31;
  const float* cb = ctx + ((size_t)(b * 8 + h)) * 1024 + d * 32;
  const float* wr = wout + (size_t)o * 256 + h * 32;
  float s = 0.f;
#pragma unroll
  for (int e = 0; e < 32; ++e) s += wr[e] * cb[e];
  s *= (1.f / Ssum[b * 256 + tid]);
  wctxb[((size_t)b * 256 + o) * 256 + tid] = f2b(s);
}

// ------------------------------------------------------------------
// K6: out = wctxb @ qsm + bias + x.  Pure GEMM (qT pre-softmaxed),
// 256x128 tile, 512 thr, single 48KB buffer (r7 proven).
// ------------------------------------------------------------------
__global__ __launch_bounds__(512, 4) void out_gemm(const unsigned short* __restrict__ wctxb,
                                                   const unsigned short* __restrict__ qT,
                                                   const float* __restrict__ bout,
                                                   const float* __restrict__ x,
                                                   float* __restrict__ out) {
  __shared__ unsigned short smem[24576];   // 48KB: As [0,16384), Bs [16384,24576)
  unsigned short* As = smem;               // 256 rows x 64c
  unsigned short* Bs = smem + 16384;       // 128 rows x 64c
  int bid = blockIdx.x;
  int L = (bid & 7) * 128 + (bid >> 3);    // 1024 = 8*128, bijective
  int b = L >> 8, nt = L & 255;
  int n0 = nt * 128;
  int tid = threadIdx.x;
  int w = tid >> 6, l = tid & 63;
  int hi = (l >> 4) & 3, lo = l & 15;
  int wo = w >> 1, wn = w & 1;
  int lr = l >> 3, lj = l & 7;
  int srcj = lj ^ lr;
  const unsigned short* Abase = wctxb + (size_t)b * 65536;
  const unsigned short* Bbase = qT + ((size_t)(b * NTOK + n0)) * 256;

  f32x4 acc[4][4];
#pragma unroll
  for (int s = 0; s < 4; ++s)
#pragma unroll
    for (int n = 0; n < 4; ++n) acc[s][n] = (f32x4){0.f, 0.f, 0.f, 0.f};

  for (int c0 = 0; c0 < 256; c0 += 64) {
    __syncthreads();
#pragma unroll
    for (int q = 0; q < 4; ++q) {          // A: 32 chunks of 1KB
      int chunk = w * 4 + q; int row = chunk * 8 + lr;
      stage16(Abase + (size_t)row * 256 + c0 + srcj * 8, As + chunk * 512, l);
    }
#pragma unroll
    for (int q = 0; q < 2; ++q) {          // B: 16 chunks
      int chunk = w * 2 + q; int row = chunk * 8 + lr;
      stage16(Bbase + (size_t)row * 256 + c0 + srcj * 8, Bs + chunk * 512, l);
    }
    __syncthreads();
#pragma unroll
    for (int t = 0; t < 2; ++t) {
      s16x8 af[4], bf[4];
#pragma unroll
      for (int s = 0; s < 4; ++s) {
        int row = wo * 64 + s * 16 + lo;
        int phys = (t * 4 + hi) ^ (row & 7);
        af[s] = *reinterpret_cast<const s16x8*>(&As[row * 64 + phys * 8]);
      }
#pragma unroll
      for (int n = 0; n < 4; ++n) {
        int row = wn * 64 + n * 16 + lo;
        int phys = (t * 4 + hi) ^ (row & 7);
        bf[n] = *reinterpret_cast<const s16x8*>(&Bs[row * 64 + phys * 8]);
      }
#pragma unroll
      for (int s = 0; s < 4; ++s)
#pragma unroll
        for (int n = 0; n < 4; ++n)
          acc[s][n] = __builtin_amdgcn_mfma_f32_16x16x32_bf16(af[s], bf[n], acc[s][n], 0, 0, 0);
    }
  }

  const float* xb = x + (size_t)b * 256 * NTOK;
#pragma unroll
  for (int s = 0; s < 4; ++s)
#pragma unroll
    for (int i = 0; i < 4; ++i) {
      int o = wo * 64 + s * 16 + hi * 4 + i;
      float bo = bout[o];
#pragma unroll
      for (int n = 0; n < 4; ++n) {
        int nn = n0 + wn * 64 + n * 16 + lo;
        out[((size_t)b * 256 + o) * NTOK + nn] = acc[s][n][i] + bo + xb[(size_t)o * NTOK + nn];
      }
    }
}

// ------------------------------------------------------------------
extern "C" void kernel_launch(void* const* d_in, const int* in_sizes, int n_in,
                              void* d_out, int out_size, void* d_ws, size_t ws_size,
                              hipStream_t stream) {
  const float* x     = (const float*)d_in[0];
  const float* gamma = (const float*)d_in[1];
  const float* beta  = (const float*)d_in[2];
  const float* wqkv  = (const float*)d_in[3];
  const float* wout  = (const float*)d_in[4];
  const float* bout  = (const float*)d_in[5];
  float* out = (float*)d_out;

  if (ws_size < WS_NEEDED) return;

  char* ws = (char*)d_ws;
  float* gstat        = (float*)(ws + OFF_GSTAT);
  unsigned int* kmk   = (unsigned int*)(ws + OFF_KMK);
  float* Ssum         = (float*)(ws + OFF_SSUM);
  float* ctx          = (float*)(ws + OFF_CTX);
  unsigned short* wctxb = (unsigned short*)(ws + OFF_WCTXB);
  float* biasp        = (float*)(ws + OFF_BIASP);
  unsigned short* Wp  = (unsigned short*)(ws + OFF_WP);
  unsigned short* xT  = (unsigned short*)(ws + OFF_XT);
  unsigned short* qT  = (unsigned short*)(ws + OFF_QT);
  unsigned short* kvb = (unsigned short*)(ws + OFF_KVB);

  // zero: gstat, kmk (0 < all encoded floats), Ssum, ctx
  hipMemsetAsync(ws, 0, OFF_CTX + 131072u, stream);

  gn_fused  <<<dim3(512, 4), 256, 0, stream>>>(x, gstat, xT);
  fold_w    <<<dim3(768, 4), 256, 0, stream>>>(wqkv, gamma, beta, gstat, Wp, biasp);
  qkv_gemm  <<<3072, 512, 0, stream>>>(Wp, biasp, xT, qT, kvb, kmk);
  context_partial<<<dim3(32, 32), 256, 0, stream>>>(kvb, kmk, ctx, Ssum);
  make_wctx <<<dim3(256, 4), 256, 0, stream>>>(wout, ctx, Ssum, wctxb);
  out_gemm  <<<1024, 512, 0, stream>>>(wctxb, qT, bout, x, out);
}

// Round 10
// 284.068 us; speedup vs baseline: 1.2328x; 1.1912x over previous
//
#include <hip/hip_runtime.h>
#include <hip/hip_bf16.h>
#include <math.h>

#define NTOK  32768
#define GNEPS 1e-5f

typedef __attribute__((ext_vector_type(4))) float f32x4;
typedef __attribute__((ext_vector_type(8))) short s16x8;
typedef __attribute__((ext_vector_type(4))) unsigned short u16x4;

__device__ __forceinline__ unsigned short f2b(float f) {
  unsigned int u = __float_as_uint(f);
  unsigned int r = (u + 0x7FFFu + ((u >> 16) & 1u)) >> 16;
  return (unsigned short)r;
}
__device__ __forceinline__ float b2f(unsigned short s) {
  return __uint_as_float(((unsigned int)s) << 16);
}

__device__ __forceinline__ void stage16(const unsigned short* g, unsigned short* ldsChunkBase, int lane) {
#if __has_builtin(__builtin_amdgcn_global_load_lds)
  __builtin_amdgcn_global_load_lds((const __attribute__((address_space(1))) void*)g,
                                   (__attribute__((address_space(3))) void*)ldsChunkBase, 16, 0, 0);
#else
  *(s16x8*)((char*)ldsChunkBase + lane * 16) = *(const s16x8*)g;
#endif
}

// ---- workspace layout (bytes) ----
#define OFF_GSTAT   0u                // 32 f32
#define OFF_SSUM    4224u             // 1024 f32 k-softmax denominators
#define OFF_CTX     8320u             // 4*8*32*32 f32 = 131072 (unnormalized)
#define OFF_WCTXB   139392u           // 4*256*256 bf16 = 524288
#define OFF_BIASP   663680u           // 4*768 f32 = 12288
#define OFF_WP      675968u           // 768*256*4 bf16 = 1572864
#define OFF_XT      2248832u          // 4*32768*256 bf16 = 67108864 (raw x, [n][c])
#define OFF_QT      69357696u         // 4*32768*256 bf16 = 67108864 (SOFTMAXED q, [n][c'])
#define OFF_KVB     136466560u        // 4*512*32768 bf16 = 134217728
#define WS_NEEDED   (OFF_KVB + 134217728ull)

// ------------------------------------------------------------------
// K1: fused GN stats + raw-x bf16 cast + transpose -> xT [b][n][c]
// s1 u16[256][64] with rotated columns (transpose read 2-way = free).
// ------------------------------------------------------------------
__global__ __launch_bounds__(256) void gn_fused(const float* __restrict__ x,
                                                float* __restrict__ gstat,
                                                unsigned short* __restrict__ xT) {
  __shared__ unsigned short s1[256 * 64];
  __shared__ float rs[4][4], rq[4][4];
  int b = blockIdx.y;
  int n0 = blockIdx.x * 64;
  int tid = threadIdx.x;
  const float* xb = x + (size_t)b * 256 * NTOK;
  float s[4] = {0.f, 0.f, 0.f, 0.f}, sq[4] = {0.f, 0.f, 0.f, 0.f};
#pragma unroll
  for (int it = 0; it < 16; ++it) {
    int idx = tid + it * 256;          // 4096 = 256c x 16 quads
    int c = idx >> 4, q = idx & 15;
    f32x4 v = *reinterpret_cast<const f32x4*>(&xb[(size_t)c * NTOK + n0 + q * 4]);
    const int g = it >> 2;             // compile-time group
    s[g]  += v.x + v.y + v.z + v.w;
    sq[g] += v.x * v.x + v.y * v.y + v.z * v.z + v.w * v.w;
    u16x4 o = { f2b(v.x), f2b(v.y), f2b(v.z), f2b(v.w) };
    int phys = (q * 4 + (c >> 3) * 4) & 63;
    *reinterpret_cast<u16x4*>(&s1[c * 64 + phys]) = o;
  }
  int lane = tid & 63, w = tid >> 6;
#pragma unroll
  for (int g = 0; g < 4; ++g) {
    float a = s[g], bq = sq[g];
    for (int o = 32; o > 0; o >>= 1) { a += __shfl_down(a, o); bq += __shfl_down(bq, o); }
    if (lane == 0) { rs[w][g] = a; rq[w][g] = bq; }
  }
  __syncthreads();
  if (tid < 8) {
    int g = tid >> 1, part = tid & 1;
    float v = part ? (rq[0][g] + rq[1][g] + rq[2][g] + rq[3][g])
                   : (rs[0][g] + rs[1][g] + rs[2][g] + rs[3][g]);
    atomicAdd(&gstat[2 * (b * 4 + g) + part], v);
  }
#pragma unroll
  for (int it = 0; it < 8; ++it) {
    int task = tid + it * 256;         // 2048 = 64n x 32 octets
    int n = task >> 5, oc = task & 31;
    int phys = (n + oc * 4) & 63;
    s16x8 pk;
#pragma unroll
    for (int i = 0; i < 8; ++i) pk[i] = (short)s1[(oc * 8 + i) * 64 + phys];
    *reinterpret_cast<s16x8*>(&xT[((size_t)(b * NTOK + n0 + n)) * 256 + oc * 8]) = pk;
  }
}

// ------------------------------------------------------------------
// K2: finalize stats + fold GN into weights
// ------------------------------------------------------------------
__global__ __launch_bounds__(256) void fold_w(const float* __restrict__ wqkv,
                                              const float* __restrict__ gamma,
                                              const float* __restrict__ beta,
                                              const float* __restrict__ gstat,
                                              unsigned short* __restrict__ Wp,
                                              float* __restrict__ biasp) {
  int o = blockIdx.x, b = blockIdx.y;
  int c = threadIdx.x;
  int g = c >> 6;
  const float cnt = 64.f * (float)NTOK;
  float mu  = gstat[2 * (b * 4 + g)] / cnt;
  float var = gstat[2 * (b * 4 + g) + 1] / cnt - mu * mu;
  float rsig = rsqrtf(var + GNEPS);
  float wv = wqkv[(size_t)o * 256 + c];
  float A = gamma[c] * rsig;
  float Bc = beta[c] - mu * A;
  Wp[((size_t)b * 768 + o) * 256 + c] = f2b(wv * A);
  float t = wv * Bc;
  int lane = c & 63, w = c >> 6;
  for (int off = 32; off > 0; off >>= 1) t += __shfl_down(t, off);
  __shared__ float red[4];
  if (lane == 0) red[w] = t;
  __syncthreads();
  if (c == 0) biasp[b * 768 + o] = red[0] + red[1] + red[2] + red[3];
}

// ------------------------------------------------------------------
// K3: qkv GEMM, 256x128 tile (o x n), 512 thr, m97 2-barrier loop,
// single 48KB buffer. Epilogue: bias; q -> softmax over d -> qT[n][o];
// k/v -> kvb[row][n]. (No k-max needed: exp(k) is computed unshifted.)
// ------------------------------------------------------------------
__global__ __launch_bounds__(512, 4) void qkv_gemm(const unsigned short* __restrict__ Wp,
                                                   const float* __restrict__ biasp,
                                                   const unsigned short* __restrict__ xT,
                                                   unsigned short* __restrict__ qT,
                                                   unsigned short* __restrict__ kvb) {
  __shared__ unsigned short smem[24576];   // 48KB: As [0,16384), Bs [16384,24576); epilogue bounce aliases
  unsigned short* As = smem;               // 256 rows x 64c
  unsigned short* Bs = smem + 16384;       // 128 rows x 64c
  int bid = blockIdx.x;
  int L = (bid & 7) * 384 + (bid >> 3);    // chunked XCD swizzle (3072 = 8*384)
  int ot = L % 3;                          // q/k/v — adjacent L share (b,nt) => same XCD L2
  int t2 = L / 3;
  int b = t2 & 3, nt = t2 >> 2;
  int n0 = nt * 128;
  int tid = threadIdx.x;
  int w = tid >> 6, l = tid & 63;
  int hi = (l >> 4) & 3, lo = l & 15;
  int wo = w >> 1, wn = w & 1;
  int lr = l >> 3, lj = l & 7;
  int srcj = lj ^ lr;                      // pre-swizzled source slot
  const unsigned short* Abase = Wp + ((size_t)(b * 768 + ot * 256)) * 256;
  const unsigned short* Bbase = xT + ((size_t)(b * NTOK + n0)) * 256;

  f32x4 acc[4][4];
#pragma unroll
  for (int s = 0; s < 4; ++s)
#pragma unroll
    for (int n = 0; n < 4; ++n) acc[s][n] = (f32x4){0.f, 0.f, 0.f, 0.f};

  for (int c0 = 0; c0 < 256; c0 += 64) {
    __syncthreads();
#pragma unroll
    for (int q = 0; q < 4; ++q) {          // A: 32 chunks of 1KB
      int chunk = w * 4 + q; int row = chunk * 8 + lr;
      stage16(Abase + (size_t)row * 256 + c0 + srcj * 8, As + chunk * 512, l);
    }
#pragma unroll
    for (int q = 0; q < 2; ++q) {          // B: 16 chunks
      int chunk = w * 2 + q; int row = chunk * 8 + lr;
      stage16(Bbase + (size_t)row * 256 + c0 + srcj * 8, Bs + chunk * 512, l);
    }
    __syncthreads();
#pragma unroll
    for (int t = 0; t < 2; ++t) {
      s16x8 af[4], bf[4];
#pragma unroll
      for (int s = 0; s < 4; ++s) {
        int row = wo * 64 + s * 16 + lo;
        int phys = (t * 4 + hi) ^ (row & 7);
        af[s] = *reinterpret_cast<const s16x8*>(&As[row * 64 + phys * 8]);
      }
#pragma unroll
      for (int n = 0; n < 4; ++n) {
        int row = wn * 64 + n * 16 + lo;
        int phys = (t * 4 + hi) ^ (row & 7);
        bf[n] = *reinterpret_cast<const s16x8*>(&Bs[row * 64 + phys * 8]);
      }
#pragma unroll
      for (int s = 0; s < 4; ++s)
#pragma unroll
        for (int n = 0; n < 4; ++n)
          acc[s][n] = __builtin_amdgcn_mfma_f32_16x16x32_bf16(af[s], bf[n], acc[s][n], 0, 0, 0);
    }
  }

  // bias add
#pragma unroll
  for (int s = 0; s < 4; ++s)
#pragma unroll
    for (int i = 0; i < 4; ++i) {
      float bv = biasp[b * 768 + ot * 256 + wo * 64 + s * 16 + hi * 4 + i];
#pragma unroll
      for (int n = 0; n < 4; ++n) acc[s][n][i] += bv;
    }

  // ---- epilogue (bounce aliases smem) ----
  if (ot == 0) {
    // q: transpose -> bounce [64n][264], softmax over d per head, store qT[n][o]
    for (int r = 0; r < 2; ++r) {
      __syncthreads();
      if (wn == r) {
#pragma unroll
        for (int s = 0; s < 4; ++s)
#pragma unroll
          for (int n = 0; n < 4; ++n)
#pragma unroll
            for (int i = 0; i < 4; ++i) {
              int o_l = wo * 64 + s * 16 + hi * 4 + i;   // 0..255
              int n_l = n * 16 + lo;                     // 0..63
              smem[n_l * 264 + o_l] = f2b(acc[s][n][i]);
            }
      }
      __syncthreads();
      // softmax over d within head: 512 tasks = 64n x 8h
      {
        int n_l = tid >> 3, h = tid & 7;
        unsigned short* rowp = &smem[n_l * 264 + h * 32];
        float v[32];
        float m = -1e30f;
#pragma unroll
        for (int i = 0; i < 32; ++i) { v[i] = b2f(rowp[i]); m = fmaxf(m, v[i]); }
        float ssum = 0.f;
#pragma unroll
        for (int i = 0; i < 32; ++i) { v[i] = __expf(v[i] - m); ssum += v[i]; }
        float rr = 1.f / ssum;
#pragma unroll
        for (int i = 0; i < 32; ++i) rowp[i] = f2b(v[i] * rr);
      }
      __syncthreads();
#pragma unroll
      for (int it = 0; it < 4; ++it) {
        int task = tid + it * 512;                        // 2048 = 64n x 32 slots
        int n_l = task >> 5, j = task & 31;
        s16x8 v = *reinterpret_cast<const s16x8*>(&smem[n_l * 264 + j * 8]);
        *reinterpret_cast<s16x8*>(&qT[((size_t)(b * NTOK + n0 + r * 64 + n_l)) * 256 + j * 8]) = v;
      }
    }
  } else {
    // k/v: [row][n], 2 rounds over wo pairs; bounce [128o][136]
    int vbase = (ot == 1) ? 0 : 256;
    for (int r = 0; r < 2; ++r) {
      __syncthreads();
      if ((wo >> 1) == r) {
#pragma unroll
        for (int s = 0; s < 4; ++s)
#pragma unroll
          for (int n = 0; n < 4; ++n)
#pragma unroll
            for (int i = 0; i < 4; ++i) {
              int o_l = (wo & 1) * 64 + s * 16 + hi * 4 + i;  // 0..127
              int n_l = wn * 64 + n * 16 + lo;                // 0..127
              smem[o_l * 136 + n_l] = f2b(acc[s][n][i]);
            }
      }
      __syncthreads();
#pragma unroll
      for (int it = 0; it < 4; ++it) {
        int task = tid + it * 512;                        // 2048 = 128o x 16 slots
        int o_l = task >> 4, j = task & 15;
        s16x8 v = *reinterpret_cast<const s16x8*>(&smem[o_l * 136 + j * 8]);
        int row = vbase + r * 128 + o_l;
        *reinterpret_cast<s16x8*>(&kvb[((size_t)(b * 512 + row)) * NTOK + n0 + j * 8]) = v;
      }
    }
  }
}

// ------------------------------------------------------------------
// K4: context via MFMA.  ctx~[b][h](d,e) += sum_n exp(k[d,n]) * v[e,n],
// Ssum[b][h][d] += sum_n exp(k[d,n])  (ones-vector MFMA rowsum).
// Block = (512-token chunk, bh), 256 thr = 4 waves x 128 tokens.
// A-frag = exp(K) from [d][n] (row-major-k); B-frag = V from [e][n]
// (col-major-by-k) — both natural-layout fragment loads, XOR-swizzled.
// ------------------------------------------------------------------
__global__ __launch_bounds__(256) void context_mfma(const unsigned short* __restrict__ kvb,
                                                    float* __restrict__ ctx,
                                                    float* __restrict__ Ssum) {
  __shared__ unsigned short kl[32 * 512];   // exp(k) bf16, 16B-block XOR swizzle
  __shared__ unsigned short vl[32 * 512];   // v bf16, same swizzle
  int bh = blockIdx.y;
  int b = bh >> 3, h = bh & 7;
  int n0 = blockIdx.x * 512;
  int tid = threadIdx.x;
  int w = tid >> 6, l = tid & 63;
  int lo = l & 15, hi = l >> 4;
  const unsigned short* kb = kvb + (((size_t)(b * 512) + h * 32) * NTOK) + n0;
  const unsigned short* vb = kvb + (((size_t)(b * 512) + 256 + h * 32) * NTOK) + n0;

  // stage: 2048 16B-tasks per operand, 8 per thread, coalesced rows
#pragma unroll
  for (int it = 0; it < 8; ++it) {
    int task = tid + it * 256;
    int row = task >> 6, blk = task & 63;
    int phys = blk ^ (row & 7);
    s16x8 kv = *reinterpret_cast<const s16x8*>(&kb[(size_t)row * NTOK + blk * 8]);
    s16x8 vv = *reinterpret_cast<const s16x8*>(&vb[(size_t)row * NTOK + blk * 8]);
    s16x8 ke;
#pragma unroll
    for (int j = 0; j < 8; ++j) ke[j] = (short)f2b(__expf(b2f((unsigned short)kv[j])));
    *reinterpret_cast<s16x8*>(&kl[row * 512 + phys * 8]) = ke;
    *reinterpret_cast<s16x8*>(&vl[row * 512 + phys * 8]) = vv;
  }
  __syncthreads();

  f32x4 acc[2][2], accS[2];
#pragma unroll
  for (int fr = 0; fr < 2; ++fr) {
    accS[fr] = (f32x4){0.f, 0.f, 0.f, 0.f};
#pragma unroll
    for (int fc = 0; fc < 2; ++fc) acc[fr][fc] = (f32x4){0.f, 0.f, 0.f, 0.f};
  }
  s16x8 ones;
#pragma unroll
  for (int j = 0; j < 8; ++j) ones[j] = (short)0x3F80;   // bf16 1.0

  // wave's n-range: [w*128, w*128+128), 4 k-steps of 32
#pragma unroll
  for (int ks = 0; ks < 4; ++ks) {
    int nblk = w * 16 + ks * 4 + hi;       // 16B block within row
    s16x8 af[2], bf[2];
#pragma unroll
    for (int fr = 0; fr < 2; ++fr) {
      int row = fr * 16 + lo;
      int phys = nblk ^ (row & 7);
      af[fr] = *reinterpret_cast<const s16x8*>(&kl[row * 512 + phys * 8]);
      bf[fr] = *reinterpret_cast<const s16x8*>(&vl[row * 512 + phys * 8]);
    }
#pragma unroll
    for (int fr = 0; fr < 2; ++fr) {
#pragma unroll
      for (int fc = 0; fc < 2; ++fc)
        acc[fr][fc] = __builtin_amdgcn_mfma_f32_16x16x32_bf16(af[fr], bf[fc], acc[fr][fc], 0, 0, 0);
      accS[fr] = __builtin_amdgcn_mfma_f32_16x16x32_bf16(af[fr], ones, accS[fr], 0, 0, 0);
    }
  }
  __syncthreads();

  // per-wave partials -> LDS (aliases kl), then tree-sum + global atomics
  float* lpart = reinterpret_cast<float*>(kl);            // [4][1056]
  float* mine = lpart + w * 1056;
#pragma unroll
  for (int fr = 0; fr < 2; ++fr) {
#pragma unroll
    for (int fc = 0; fc < 2; ++fc)
#pragma unroll
      for (int i = 0; i < 4; ++i) {
        int row = fr * 16 + hi * 4 + i;
        int col = fc * 16 + lo;
        mine[row * 32 + col] = acc[fr][fc][i];
      }
    if (lo == 0)
#pragma unroll
      for (int i = 0; i < 4; ++i)
        mine[1024 + fr * 16 + hi * 4 + i] = accS[fr][i];
  }
  __syncthreads();
  float* cb = ctx + (size_t)bh * 1024;
  for (int i = tid; i < 1024; i += 256) {
    float v = lpart[i] + lpart[1056 + i] + lpart[2112 + i] + lpart[3168 + i];
    atomicAdd(&cb[i], v);
  }
  if (tid < 32) {
    int i = 1024 + tid;
    float v = lpart[i] + lpart[1056 + i] + lpart[2112 + i] + lpart[3168 + i];
    atomicAdd(&Ssum[b * 256 + h * 32 + tid], v);
  }
}

// ------------------------------------------------------------------
// K5: wctx_b = bf16( (1/Ssum) * wout @ ctx~ )
// ------------------------------------------------------------------
__global__ __launch_bounds__(256) void make_wctx(const float* __restrict__ wout,
                                                 const float* __restrict__ ctx,
                                                 const float* __restrict__ Ssum,
                                                 unsigned short* __restrict__ wctxb) {
  int o = blockIdx.x, b = blockIdx.y;
  int tid = threadIdx.x;
  int h = tid >> 5, d = tid & 31;
  const float* cb = ctx + ((size_t)(b * 8 + h)) * 1024 + d * 32;
  const float* wr = wout + (size_t)o * 256 + h * 32;
  float s = 0.f;
#pragma unroll
  for (int e = 0; e < 32; ++e) s += wr[e] * cb[e];
  s *= (1.f / Ssum[b * 256 + tid]);
  wctxb[((size_t)b * 256 + o) * 256 + tid] = f2b(s);
}

// ------------------------------------------------------------------
// K6: out = wctxb @ qsm + bias + x.  Pure GEMM (qT pre-softmaxed),
// 256x128 tile, 512 thr, single 48KB buffer.
// ------------------------------------------------------------------
__global__ __launch_bounds__(512, 4) void out_gemm(const unsigned short* __restrict__ wctxb,
                                                   const unsigned short* __restrict__ qT,
                                                   const float* __restrict__ bout,
                                                   const float* __restrict__ x,
                                                   float* __restrict__ out) {
  __shared__ unsigned short smem[24576];   // 48KB: As [0,16384), Bs [16384,24576)
  unsigned short* As = smem;               // 256 rows x 64c
  unsigned short* Bs = smem + 16384;       // 128 rows x 64c
  int bid = blockIdx.x;
  int L = (bid & 7) * 128 + (bid >> 3);    // 1024 = 8*128, bijective
  int b = L >> 8, nt = L & 255;
  int n0 = nt * 128;
  int tid = threadIdx.x;
  int w = tid >> 6, l = tid & 63;
  int hi = (l >> 4) & 3, lo = l & 15;
  int wo = w >> 1, wn = w & 1;
  int lr = l >> 3, lj = l & 7;
  int srcj = lj ^ lr;
  const unsigned short* Abase = wctxb + (size_t)b * 65536;
  const unsigned short* Bbase = qT + ((size_t)(b * NTOK + n0)) * 256;

  f32x4 acc[4][4];
#pragma unroll
  for (int s = 0; s < 4; ++s)
#pragma unroll
    for (int n = 0; n < 4; ++n) acc[s][n] = (f32x4){0.f, 0.f, 0.f, 0.f};

  for (int c0 = 0; c0 < 256; c0 += 64) {
    __syncthreads();
#pragma unroll
    for (int q = 0; q < 4; ++q) {          // A: 32 chunks of 1KB
      int chunk = w * 4 + q; int row = chunk * 8 + lr;
      stage16(Abase + (size_t)row * 256 + c0 + srcj * 8, As + chunk * 512, l);
    }
#pragma unroll
    for (int q = 0; q < 2; ++q) {          // B: 16 chunks
      int chunk = w * 2 + q; int row = chunk * 8 + lr;
      stage16(Bbase + (size_t)row * 256 + c0 + srcj * 8, Bs + chunk * 512, l);
    }
    __syncthreads();
#pragma unroll
    for (int t = 0; t < 2; ++t) {
      s16x8 af[4], bf[4];
#pragma unroll
      for (int s = 0; s < 4; ++s) {
        int row = wo * 64 + s * 16 + lo;
        int phys = (t * 4 + hi) ^ (row & 7);
        af[s] = *reinterpret_cast<const s16x8*>(&As[row * 64 + phys * 8]);
      }
#pragma unroll
      for (int n = 0; n < 4; ++n) {
        int row = wn * 64 + n * 16 + lo;
        int phys = (t * 4 + hi) ^ (row & 7);
        bf[n] = *reinterpret_cast<const s16x8*>(&Bs[row * 64 + phys * 8]);
      }
#pragma unroll
      for (int s = 0; s < 4; ++s)
#pragma unroll
        for (int n = 0; n < 4; ++n)
          acc[s][n] = __builtin_amdgcn_mfma_f32_16x16x32_bf16(af[s], bf[n], acc[s][n], 0, 0, 0);
    }
  }

  const float* xb = x + (size_t)b * 256 * NTOK;
#pragma unroll
  for (int s = 0; s < 4; ++s)
#pragma unroll
    for (int i = 0; i < 4; ++i) {
      int o = wo * 64 + s * 16 + hi * 4 + i;
      float bo = bout[o];
#pragma unroll
      for (int n = 0; n < 4; ++n) {
        int nn = n0 + wn * 64 + n * 16 + lo;
        out[((size_t)b * 256 + o) * NTOK + nn] = acc[s][n][i] + bo + xb[(size_t)o * NTOK + nn];
      }
    }
}

// ------------------------------------------------------------------
extern "C" void kernel_launch(void* const* d_in, const int* in_sizes, int n_in,
                              void* d_out, int out_size, void* d_ws, size_t ws_size,
                              hipStream_t stream) {
  const float* x     = (const float*)d_in[0];
  const float* gamma = (const float*)d_in[1];
  const float* beta  = (const float*)d_in[2];
  const float* wqkv  = (const float*)d_in[3];
  const float* wout  = (const float*)d_in[4];
  const float* bout  = (const float*)d_in[5];
  float* out = (float*)d_out;

  if (ws_size < WS_NEEDED) return;

  char* ws = (char*)d_ws;
  float* gstat        = (float*)(ws + OFF_GSTAT);
  float* Ssum         = (float*)(ws + OFF_SSUM);
  float* ctx          = (float*)(ws + OFF_CTX);
  unsigned short* wctxb = (unsigned short*)(ws + OFF_WCTXB);
  float* biasp        = (float*)(ws + OFF_BIASP);
  unsigned short* Wp  = (unsigned short*)(ws + OFF_WP);
  unsigned short* xT  = (unsigned short*)(ws + OFF_XT);
  unsigned short* qT  = (unsigned short*)(ws + OFF_QT);
  unsigned short* kvb = (unsigned short*)(ws + OFF_KVB);

  // zero: gstat, Ssum, ctx
  hipMemsetAsync(ws, 0, OFF_CTX + 131072u, stream);

  gn_fused  <<<dim3(512, 4), 256, 0, stream>>>(x, gstat, xT);
  fold_w    <<<dim3(768, 4), 256, 0, stream>>>(wqkv, gamma, beta, gstat, Wp, biasp);
  qkv_gemm  <<<3072, 512, 0, stream>>>(Wp, biasp, xT, qT, kvb);
  context_mfma<<<dim3(64, 32), 256, 0, stream>>>(kvb, ctx, Ssum);
  make_wctx <<<dim3(256, 4), 256, 0, stream>>>(wout, ctx, Ssum, wctxb);
  out_gemm  <<<1024, 512, 0, stream>>>(wctxb, qT, bout, x, out);
}

// Round 11
// 253.616 us; speedup vs baseline: 1.3809x; 1.1201x over previous
//
#include <hip/hip_runtime.h>
#include <hip/hip_bf16.h>
#include <math.h>

#define NTOK  32768
#define GNEPS 1e-5f

typedef __attribute__((ext_vector_type(4))) float f32x4;
typedef __attribute__((ext_vector_type(8))) short s16x8;
typedef __attribute__((ext_vector_type(4))) unsigned short u16x4;

__device__ __forceinline__ unsigned short f2b(float f) {
  unsigned int u = __float_as_uint(f);
  unsigned int r = (u + 0x7FFFu + ((u >> 16) & 1u)) >> 16;
  return (unsigned short)r;
}
__device__ __forceinline__ float b2f(unsigned short s) {
  return __uint_as_float(((unsigned int)s) << 16);
}

__device__ __forceinline__ void stage16(const unsigned short* g, unsigned short* ldsChunkBase, int lane) {
#if __has_builtin(__builtin_amdgcn_global_load_lds)
  __builtin_amdgcn_global_load_lds((const __attribute__((address_space(1))) void*)g,
                                   (__attribute__((address_space(3))) void*)ldsChunkBase, 16, 0, 0);
#else
  *(s16x8*)((char*)ldsChunkBase + lane * 16) = *(const s16x8*)g;
#endif
}

// ---- workspace layout (bytes) ----
#define OFF_GSTAT   0u                // 32 f32
#define OFF_SSUM    4224u             // 1024 f32 k-softmax denominators
#define OFF_CTX     8320u             // 4*8*32*32 f32 = 131072 (unnormalized)
#define OFF_WCTXB   139392u           // 4*256*256 bf16 = 524288
#define OFF_BIASP   663680u           // 4*768 f32 = 12288
#define OFF_WP      675968u           // 768*256*4 bf16 = 1572864
#define OFF_XT      2248832u          // 4*32768*256 bf16 = 67108864 (raw x, [n][c])
#define OFF_QT      69357696u         // 4*32768*256 bf16 = 67108864 (SOFTMAXED q, [n][c'])
#define OFF_KVB     136466560u        // 4*512*32768 bf16 = 134217728
#define WS_NEEDED   (OFF_KVB + 134217728ull)

// ------------------------------------------------------------------
// K1: fused GN stats + raw-x bf16 cast + transpose -> xT [b][n][c]
// s1 u16[256][64] with rotated columns (transpose read 2-way = free).
// ------------------------------------------------------------------
__global__ __launch_bounds__(256) void gn_fused(const float* __restrict__ x,
                                                float* __restrict__ gstat,
                                                unsigned short* __restrict__ xT) {
  __shared__ unsigned short s1[256 * 64];
  __shared__ float rs[4][4], rq[4][4];
  int b = blockIdx.y;
  int n0 = blockIdx.x * 64;
  int tid = threadIdx.x;
  const float* xb = x + (size_t)b * 256 * NTOK;
  float s[4] = {0.f, 0.f, 0.f, 0.f}, sq[4] = {0.f, 0.f, 0.f, 0.f};
#pragma unroll
  for (int it = 0; it < 16; ++it) {
    int idx = tid + it * 256;          // 4096 = 256c x 16 quads
    int c = idx >> 4, q = idx & 15;
    f32x4 v = *reinterpret_cast<const f32x4*>(&xb[(size_t)c * NTOK + n0 + q * 4]);
    const int g = it >> 2;             // compile-time group
    s[g]  += v.x + v.y + v.z + v.w;
    sq[g] += v.x * v.x + v.y * v.y + v.z * v.z + v.w * v.w;
    u16x4 o = { f2b(v.x), f2b(v.y), f2b(v.z), f2b(v.w) };
    int phys = (q * 4 + (c >> 3) * 4) & 63;
    *reinterpret_cast<u16x4*>(&s1[c * 64 + phys]) = o;
  }
  int lane = tid & 63, w = tid >> 6;
#pragma unroll
  for (int g = 0; g < 4; ++g) {
    float a = s[g], bq = sq[g];
    for (int o = 32; o > 0; o >>= 1) { a += __shfl_down(a, o); bq += __shfl_down(bq, o); }
    if (lane == 0) { rs[w][g] = a; rq[w][g] = bq; }
  }
  __syncthreads();
  if (tid < 8) {
    int g = tid >> 1, part = tid & 1;
    float v = part ? (rq[0][g] + rq[1][g] + rq[2][g] + rq[3][g])
                   : (rs[0][g] + rs[1][g] + rs[2][g] + rs[3][g]);
    atomicAdd(&gstat[2 * (b * 4 + g) + part], v);
  }
#pragma unroll
  for (int it = 0; it < 8; ++it) {
    int task = tid + it * 256;         // 2048 = 64n x 32 octets
    int n = task >> 5, oc = task & 31;
    int phys = (n + oc * 4) & 63;
    s16x8 pk;
#pragma unroll
    for (int i = 0; i < 8; ++i) pk[i] = (short)s1[(oc * 8 + i) * 64 + phys];
    *reinterpret_cast<s16x8*>(&xT[((size_t)(b * NTOK + n0 + n)) * 256 + oc * 8]) = pk;
  }
}

// ------------------------------------------------------------------
// K2: finalize stats + fold GN into weights
// ------------------------------------------------------------------
__global__ __launch_bounds__(256) void fold_w(const float* __restrict__ wqkv,
                                              const float* __restrict__ gamma,
                                              const float* __restrict__ beta,
                                              const float* __restrict__ gstat,
                                              unsigned short* __restrict__ Wp,
                                              float* __restrict__ biasp) {
  int o = blockIdx.x, b = blockIdx.y;
  int c = threadIdx.x;
  int g = c >> 6;
  const float cnt = 64.f * (float)NTOK;
  float mu  = gstat[2 * (b * 4 + g)] / cnt;
  float var = gstat[2 * (b * 4 + g) + 1] / cnt - mu * mu;
  float rsig = rsqrtf(var + GNEPS);
  float wv = wqkv[(size_t)o * 256 + c];
  float A = gamma[c] * rsig;
  float Bc = beta[c] - mu * A;
  Wp[((size_t)b * 768 + o) * 256 + c] = f2b(wv * A);
  float t = wv * Bc;
  int lane = c & 63, w = c >> 6;
  for (int off = 32; off > 0; off >>= 1) t += __shfl_down(t, off);
  __shared__ float red[4];
  if (lane == 0) red[w] = t;
  __syncthreads();
  if (c == 0) biasp[b * 768 + o] = red[0] + red[1] + red[2] + red[3];
}

// ------------------------------------------------------------------
// K3: qkv GEMM, 256x128 tile (o x n), 512 thr, m97 2-barrier loop,
// single 48KB buffer. Epilogue: bias; q -> softmax over d -> qT[n][o];
// k/v -> kvb[row][n]. (exp(k) computed unshifted downstream.)
// ------------------------------------------------------------------
__global__ __launch_bounds__(512, 4) void qkv_gemm(const unsigned short* __restrict__ Wp,
                                                   const float* __restrict__ biasp,
                                                   const unsigned short* __restrict__ xT,
                                                   unsigned short* __restrict__ qT,
                                                   unsigned short* __restrict__ kvb) {
  __shared__ unsigned short smem[24576];   // 48KB: As [0,16384), Bs [16384,24576); epilogue bounce aliases
  unsigned short* As = smem;               // 256 rows x 64c
  unsigned short* Bs = smem + 16384;       // 128 rows x 64c
  int bid = blockIdx.x;
  int L = (bid & 7) * 384 + (bid >> 3);    // chunked XCD swizzle (3072 = 8*384)
  int ot = L % 3;                          // q/k/v — adjacent L share (b,nt) => same XCD L2
  int t2 = L / 3;
  int b = t2 & 3, nt = t2 >> 2;
  int n0 = nt * 128;
  int tid = threadIdx.x;
  int w = tid >> 6, l = tid & 63;
  int hi = (l >> 4) & 3, lo = l & 15;
  int wo = w >> 1, wn = w & 1;
  int lr = l >> 3, lj = l & 7;
  int srcj = lj ^ lr;                      // pre-swizzled source slot
  const unsigned short* Abase = Wp + ((size_t)(b * 768 + ot * 256)) * 256;
  const unsigned short* Bbase = xT + ((size_t)(b * NTOK + n0)) * 256;

  f32x4 acc[4][4];
#pragma unroll
  for (int s = 0; s < 4; ++s)
#pragma unroll
    for (int n = 0; n < 4; ++n) acc[s][n] = (f32x4){0.f, 0.f, 0.f, 0.f};

  for (int c0 = 0; c0 < 256; c0 += 64) {
    __syncthreads();
#pragma unroll
    for (int q = 0; q < 4; ++q) {          // A: 32 chunks of 1KB
      int chunk = w * 4 + q; int row = chunk * 8 + lr;
      stage16(Abase + (size_t)row * 256 + c0 + srcj * 8, As + chunk * 512, l);
    }
#pragma unroll
    for (int q = 0; q < 2; ++q) {          // B: 16 chunks
      int chunk = w * 2 + q; int row = chunk * 8 + lr;
      stage16(Bbase + (size_t)row * 256 + c0 + srcj * 8, Bs + chunk * 512, l);
    }
    __syncthreads();
#pragma unroll
    for (int t = 0; t < 2; ++t) {
      s16x8 af[4], bf[4];
#pragma unroll
      for (int s = 0; s < 4; ++s) {
        int row = wo * 64 + s * 16 + lo;
        int phys = (t * 4 + hi) ^ (row & 7);
        af[s] = *reinterpret_cast<const s16x8*>(&As[row * 64 + phys * 8]);
      }
#pragma unroll
      for (int n = 0; n < 4; ++n) {
        int row = wn * 64 + n * 16 + lo;
        int phys = (t * 4 + hi) ^ (row & 7);
        bf[n] = *reinterpret_cast<const s16x8*>(&Bs[row * 64 + phys * 8]);
      }
#pragma unroll
      for (int s = 0; s < 4; ++s)
#pragma unroll
        for (int n = 0; n < 4; ++n)
          acc[s][n] = __builtin_amdgcn_mfma_f32_16x16x32_bf16(af[s], bf[n], acc[s][n], 0, 0, 0);
    }
  }

  // bias add
#pragma unroll
  for (int s = 0; s < 4; ++s)
#pragma unroll
    for (int i = 0; i < 4; ++i) {
      float bv = biasp[b * 768 + ot * 256 + wo * 64 + s * 16 + hi * 4 + i];
#pragma unroll
      for (int n = 0; n < 4; ++n) acc[s][n][i] += bv;
    }

  // ---- epilogue (bounce aliases smem) ----
  if (ot == 0) {
    // q: transpose -> bounce [64n][264], softmax over d per head, store qT[n][o]
    for (int r = 0; r < 2; ++r) {
      __syncthreads();
      if (wn == r) {
#pragma unroll
        for (int s = 0; s < 4; ++s)
#pragma unroll
          for (int n = 0; n < 4; ++n)
#pragma unroll
            for (int i = 0; i < 4; ++i) {
              int o_l = wo * 64 + s * 16 + hi * 4 + i;   // 0..255
              int n_l = n * 16 + lo;                     // 0..63
              smem[n_l * 264 + o_l] = f2b(acc[s][n][i]);
            }
      }
      __syncthreads();
      // softmax over d within head: 512 tasks = 64n x 8h
      {
        int n_l = tid >> 3, h = tid & 7;
        unsigned short* rowp = &smem[n_l * 264 + h * 32];
        float v[32];
        float m = -1e30f;
#pragma unroll
        for (int i = 0; i < 32; ++i) { v[i] = b2f(rowp[i]); m = fmaxf(m, v[i]); }
        float ssum = 0.f;
#pragma unroll
        for (int i = 0; i < 32; ++i) { v[i] = __expf(v[i] - m); ssum += v[i]; }
        float rr = 1.f / ssum;
#pragma unroll
        for (int i = 0; i < 32; ++i) rowp[i] = f2b(v[i] * rr);
      }
      __syncthreads();
#pragma unroll
      for (int it = 0; it < 4; ++it) {
        int task = tid + it * 512;                        // 2048 = 64n x 32 slots
        int n_l = task >> 5, j = task & 31;
        s16x8 v = *reinterpret_cast<const s16x8*>(&smem[n_l * 264 + j * 8]);
        *reinterpret_cast<s16x8*>(&qT[((size_t)(b * NTOK + n0 + r * 64 + n_l)) * 256 + j * 8]) = v;
      }
    }
  } else {
    // k/v: [row][n], 2 rounds over wo pairs; bounce [128o][136]
    int vbase = (ot == 1) ? 0 : 256;
    for (int r = 0; r < 2; ++r) {
      __syncthreads();
      if ((wo >> 1) == r) {
#pragma unroll
        for (int s = 0; s < 4; ++s)
#pragma unroll
          for (int n = 0; n < 4; ++n)
#pragma unroll
            for (int i = 0; i < 4; ++i) {
              int o_l = (wo & 1) * 64 + s * 16 + hi * 4 + i;  // 0..127
              int n_l = wn * 64 + n * 16 + lo;                // 0..127
              smem[o_l * 136 + n_l] = f2b(acc[s][n][i]);
            }
      }
      __syncthreads();
#pragma unroll
      for (int it = 0; it < 4; ++it) {
        int task = tid + it * 512;                        // 2048 = 128o x 16 slots
        int o_l = task >> 4, j = task & 15;
        s16x8 v = *reinterpret_cast<const s16x8*>(&smem[o_l * 136 + j * 8]);
        int row = vbase + r * 128 + o_l;
        *reinterpret_cast<s16x8*>(&kvb[((size_t)(b * 512 + row)) * NTOK + n0 + j * 8]) = v;
      }
    }
  }
}

// ------------------------------------------------------------------
// K4: context via MFMA.  ctx~[b][h](d,e) += sum_n exp(k[d,n]) * v[e,n],
// Ssum[b][h][d] += sum_n exp  (ones-vector MFMA rowsum).
// ------------------------------------------------------------------
__global__ __launch_bounds__(256) void context_mfma(const unsigned short* __restrict__ kvb,
                                                    float* __restrict__ ctx,
                                                    float* __restrict__ Ssum) {
  __shared__ unsigned short kl[32 * 512];   // exp(k) bf16, 16B-block XOR swizzle
  __shared__ unsigned short vl[32 * 512];   // v bf16, same swizzle
  int bh = blockIdx.y;
  int b = bh >> 3, h = bh & 7;
  int n0 = blockIdx.x * 512;
  int tid = threadIdx.x;
  int w = tid >> 6, l = tid & 63;
  int lo = l & 15, hi = l >> 4;
  const unsigned short* kb = kvb + (((size_t)(b * 512) + h * 32) * NTOK) + n0;
  const unsigned short* vb = kvb + (((size_t)(b * 512) + 256 + h * 32) * NTOK) + n0;

#pragma unroll
  for (int it = 0; it < 8; ++it) {
    int task = tid + it * 256;
    int row = task >> 6, blk = task & 63;
    int phys = blk ^ (row & 7);
    s16x8 kv = *reinterpret_cast<const s16x8*>(&kb[(size_t)row * NTOK + blk * 8]);
    s16x8 vv = *reinterpret_cast<const s16x8*>(&vb[(size_t)row * NTOK + blk * 8]);
    s16x8 ke;
#pragma unroll
    for (int j = 0; j < 8; ++j) ke[j] = (short)f2b(__expf(b2f((unsigned short)kv[j])));
    *reinterpret_cast<s16x8*>(&kl[row * 512 + phys * 8]) = ke;
    *reinterpret_cast<s16x8*>(&vl[row * 512 + phys * 8]) = vv;
  }
  __syncthreads();

  f32x4 acc[2][2], accS[2];
#pragma unroll
  for (int fr = 0; fr < 2; ++fr) {
    accS[fr] = (f32x4){0.f, 0.f, 0.f, 0.f};
#pragma unroll
    for (int fc = 0; fc < 2; ++fc) acc[fr][fc] = (f32x4){0.f, 0.f, 0.f, 0.f};
  }
  s16x8 ones;
#pragma unroll
  for (int j = 0; j < 8; ++j) ones[j] = (short)0x3F80;   // bf16 1.0

#pragma unroll
  for (int ks = 0; ks < 4; ++ks) {
    int nblk = w * 16 + ks * 4 + hi;
    s16x8 af[2], bf[2];
#pragma unroll
    for (int fr = 0; fr < 2; ++fr) {
      int row = fr * 16 + lo;
      int phys = nblk ^ (row & 7);
      af[fr] = *reinterpret_cast<const s16x8*>(&kl[row * 512 + phys * 8]);
      bf[fr] = *reinterpret_cast<const s16x8*>(&vl[row * 512 + phys * 8]);
    }
#pragma unroll
    for (int fr = 0; fr < 2; ++fr) {
#pragma unroll
      for (int fc = 0; fc < 2; ++fc)
        acc[fr][fc] = __builtin_amdgcn_mfma_f32_16x16x32_bf16(af[fr], bf[fc], acc[fr][fc], 0, 0, 0);
      accS[fr] = __builtin_amdgcn_mfma_f32_16x16x32_bf16(af[fr], ones, accS[fr], 0, 0, 0);
    }
  }
  __syncthreads();

  float* lpart = reinterpret_cast<float*>(kl);            // [4][1056]
  float* mine = lpart + w * 1056;
#pragma unroll
  for (int fr = 0; fr < 2; ++fr) {
#pragma unroll
    for (int fc = 0; fc < 2; ++fc)
#pragma unroll
      for (int i = 0; i < 4; ++i) {
        int row = fr * 16 + hi * 4 + i;
        int col = fc * 16 + lo;
        mine[row * 32 + col] = acc[fr][fc][i];
      }
    if (lo == 0)
#pragma unroll
      for (int i = 0; i < 4; ++i)
        mine[1024 + fr * 16 + hi * 4 + i] = accS[fr][i];
  }
  __syncthreads();
  float* cb = ctx + (size_t)bh * 1024;
  for (int i = tid; i < 1024; i += 256) {
    float v = lpart[i] + lpart[1056 + i] + lpart[2112 + i] + lpart[3168 + i];
    atomicAdd(&cb[i], v);
  }
  if (tid < 32) {
    int i = 1024 + tid;
    float v = lpart[i] + lpart[1056 + i] + lpart[2112 + i] + lpart[3168 + i];
    atomicAdd(&Ssum[b * 256 + h * 32 + tid], v);
  }
}

// ------------------------------------------------------------------
// K5: wctx_b = bf16( (1/Ssum) * wout @ ctx~ )
// ------------------------------------------------------------------
__global__ __launch_bounds__(256) void make_wctx(const float* __restrict__ wout,
                                                 const float* __restrict__ ctx,
                                                 const float* __restrict__ Ssum,
                                                 unsigned short* __restrict__ wctxb) {
  int o = blockIdx.x, b = blockIdx.y;
  int tid = threadIdx.x;
  int h = tid >> 5, d = tid & 31;
  const float* cb = ctx + ((size_t)(b * 8 + h)) * 1024 + d * 32;
  const float* wr = wout + (size_t)o * 256 + h * 32;
  float s = 0.f;
#pragma unroll
  for (int e = 0; e < 32; ++e) s += wr[e] * cb[e];
  s *= (1.f / Ssum[b * 256 + tid]);
  wctxb[((size_t)b * 256 + o) * 256 + tid] = f2b(s);
}

// ------------------------------------------------------------------
// K6: out = wctxb @ qsm + bias + x.  Pure GEMM; epilogue now goes through
// an LDS f32 bounce [64][132] so the residual read + output write are
// coalesced f32x4 (16B/lane) instead of scalar f32.
// ------------------------------------------------------------------
__global__ __launch_bounds__(512, 4) void out_gemm(const unsigned short* __restrict__ wctxb,
                                                   const unsigned short* __restrict__ qT,
                                                   const float* __restrict__ bout,
                                                   const float* __restrict__ x,
                                                   float* __restrict__ out) {
  __shared__ unsigned short smem[24576];   // 48KB: As [0,16384), Bs [16384,24576); f32 bounce aliases
  unsigned short* As = smem;               // 256 rows x 64c
  unsigned short* Bs = smem + 16384;       // 128 rows x 64c
  int bid = blockIdx.x;
  int L = (bid & 7) * 128 + (bid >> 3);    // 1024 = 8*128, bijective
  int b = L >> 8, nt = L & 255;
  int n0 = nt * 128;
  int tid = threadIdx.x;
  int w = tid >> 6, l = tid & 63;
  int hi = (l >> 4) & 3, lo = l & 15;
  int wo = w >> 1, wn = w & 1;
  int lr = l >> 3, lj = l & 7;
  int srcj = lj ^ lr;
  const unsigned short* Abase = wctxb + (size_t)b * 65536;
  const unsigned short* Bbase = qT + ((size_t)(b * NTOK + n0)) * 256;

  f32x4 acc[4][4];
#pragma unroll
  for (int s = 0; s < 4; ++s)
#pragma unroll
    for (int n = 0; n < 4; ++n) acc[s][n] = (f32x4){0.f, 0.f, 0.f, 0.f};

  for (int c0 = 0; c0 < 256; c0 += 64) {
    __syncthreads();
#pragma unroll
    for (int q = 0; q < 4; ++q) {          // A: 32 chunks of 1KB
      int chunk = w * 4 + q; int row = chunk * 8 + lr;
      stage16(Abase + (size_t)row * 256 + c0 + srcj * 8, As + chunk * 512, l);
    }
#pragma unroll
    for (int q = 0; q < 2; ++q) {          // B: 16 chunks
      int chunk = w * 2 + q; int row = chunk * 8 + lr;
      stage16(Bbase + (size_t)row * 256 + c0 + srcj * 8, Bs + chunk * 512, l);
    }
    __syncthreads();
#pragma unroll
    for (int t = 0; t < 2; ++t) {
      s16x8 af[4], bf[4];
#pragma unroll
      for (int s = 0; s < 4; ++s) {
        int row = wo * 64 + s * 16 + lo;
        int phys = (t * 4 + hi) ^ (row & 7);
        af[s] = *reinterpret_cast<const s16x8*>(&As[row * 64 + phys * 8]);
      }
#pragma unroll
      for (int n = 0; n < 4; ++n) {
        int row = wn * 64 + n * 16 + lo;
        int phys = (t * 4 + hi) ^ (row & 7);
        bf[n] = *reinterpret_cast<const s16x8*>(&Bs[row * 64 + phys * 8]);
      }
#pragma unroll
      for (int s = 0; s < 4; ++s)
#pragma unroll
        for (int n = 0; n < 4; ++n)
          acc[s][n] = __builtin_amdgcn_mfma_f32_16x16x32_bf16(af[s], bf[n], acc[s][n], 0, 0, 0);
    }
  }

  // ---- epilogue: f32 bounce [64][132] (2-way write conflict = free),
  //      then coalesced f32x4 RMW: out = acc + bias + x ----
  float* bounce = reinterpret_cast<float*>(smem);
  const float* xb = x + (size_t)b * 256 * NTOK;
  for (int r = 0; r < 4; ++r) {
    __syncthreads();
    if (wo == r) {
#pragma unroll
      for (int s = 0; s < 4; ++s)
#pragma unroll
        for (int n = 0; n < 4; ++n)
#pragma unroll
          for (int i = 0; i < 4; ++i) {
            int o_l = s * 16 + hi * 4 + i;          // 0..63
            int n_l = wn * 64 + n * 16 + lo;        // 0..127
            bounce[o_l * 132 + n_l] = acc[s][n][i];
          }
    }
    __syncthreads();
#pragma unroll
    for (int it = 0; it < 4; ++it) {
      int task = tid + it * 512;                    // 2048 = 64o x 32 quads
      int o_l = task >> 5, q4 = task & 31;
      int o = r * 64 + o_l;
      f32x4 a = *reinterpret_cast<const f32x4*>(&bounce[o_l * 132 + q4 * 4]);
      f32x4 xv = *reinterpret_cast<const f32x4*>(&xb[(size_t)o * NTOK + n0 + q4 * 4]);
      float bo = bout[o];
      f32x4 rlt = { a.x + bo + xv.x, a.y + bo + xv.y, a.z + bo + xv.z, a.w + bo + xv.w };
      *reinterpret_cast<f32x4*>(&out[((size_t)b * 256 + o) * NTOK + n0 + q4 * 4]) = rlt;
    }
  }
}

// ------------------------------------------------------------------
extern "C" void kernel_launch(void* const* d_in, const int* in_sizes, int n_in,
                              void* d_out, int out_size, void* d_ws, size_t ws_size,
                              hipStream_t stream) {
  const float* x     = (const float*)d_in[0];
  const float* gamma = (const float*)d_in[1];
  const float* beta  = (const float*)d_in[2];
  const float* wqkv  = (const float*)d_in[3];
  const float* wout  = (const float*)d_in[4];
  const float* bout  = (const float*)d_in[5];
  float* out = (float*)d_out;

  if (ws_size < WS_NEEDED) return;

  char* ws = (char*)d_ws;
  float* gstat        = (float*)(ws + OFF_GSTAT);
  float* Ssum         = (float*)(ws + OFF_SSUM);
  float* ctx          = (float*)(ws + OFF_CTX);
  unsigned short* wctxb = (unsigned short*)(ws + OFF_WCTXB);
  float* biasp        = (float*)(ws + OFF_BIASP);
  unsigned short* Wp  = (unsigned short*)(ws + OFF_WP);
  unsigned short* xT  = (unsigned short*)(ws + OFF_XT);
  unsigned short* qT  = (unsigned short*)(ws + OFF_QT);
  unsigned short* kvb = (unsigned short*)(ws + OFF_KVB);

  // zero: gstat, Ssum, ctx
  hipMemsetAsync(ws, 0, OFF_CTX + 131072u, stream);

  gn_fused  <<<dim3(512, 4), 256, 0, stream>>>(x, gstat, xT);
  fold_w    <<<dim3(768, 4), 256, 0, stream>>>(wqkv, gamma, beta, gstat, Wp, biasp);
  qkv_gemm  <<<3072, 512, 0, stream>>>(Wp, biasp, xT, qT, kvb);
  context_mfma<<<dim3(64, 32), 256, 0, stream>>>(kvb, ctx, Ssum);
  make_wctx <<<dim3(256, 4), 256, 0, stream>>>(wout, ctx, Ssum, wctxb);
  out_gemm  <<<1024, 512, 0, stream>>>(wctxb, qT, bout, x, out);
}